// Round 13
// baseline (441.510 us; speedup 1.0000x reference)
//
#include <hip/hip_runtime.h>
#include <hip/hip_bf16.h>
#include <hip/hip_fp16.h>
#include <math.h>

#define MAXH 3
#define NSB 8              // 256 nodes per bin
#define NS (1 << NSB)
#define SRCBITS 17         // n < 131072
#define SRCMASK ((1 << SRCBITS) - 1)
#define LOG2E 1.4426950408889634f
typedef unsigned int u32;
typedef unsigned long long u64;
typedef unsigned char u8;
typedef unsigned short u16;

using bf16x8 = __attribute__((ext_vector_type(8))) short;
using f32x4  = __attribute__((ext_vector_type(4))) float;

__device__ __forceinline__ float fexp2(float x) {
#if __has_builtin(__builtin_amdgcn_exp2f)
    return __builtin_amdgcn_exp2f(x);
#else
    return exp2f(x);
#endif
}
__device__ __forceinline__ u16 f2bf(float f) {  // RNE float->bf16
    u32 u = __float_as_uint(f);
    u32 r = ((u >> 16) & 1u) + 0x7fffu;
    return (u16)((u + r) >> 16);
}

// ---------------- fused init: dist + reached bitset (ballot) + bincnt zero ----------
__global__ void k_init(const int* __restrict__ seed_mask, int* dist, u64* rb64,
                       int* bincnt, int n) {
    int i = blockIdx.x * 256 + threadIdx.x;
    int lane = threadIdx.x & 63;
    bool seed = (i < n) && (seed_mask[i] == 0);
    if (i < n) dist[i] = seed ? 0 : (MAXH + 1);
    u64 b = __ballot(seed);
    if (lane == 0 && (i & ~63) < n) rb64[i >> 6] = b;
    if (blockIdx.x == 0) {
        bincnt[threadIdx.x] = 0;
        bincnt[threadIdx.x + 256] = 0;
    }
}

// ---------------- BFS step: scan in-neighbors (old bitset) -> new bitset + dist -----
__global__ void k_bfs_step(const int* __restrict__ rowptr, const int* __restrict__ csr_src,
                           const u32* __restrict__ rbOld, u64* rbNew, int* dist,
                           int h, int n) {
    int i = blockIdx.x * 256 + threadIdx.x;
    int lane = threadIdx.x & 63;
    bool reached = false;
    if (i < n) {
        reached = (rbOld[i >> 5] >> (i & 31)) & 1u;
        if (!reached) {
            int beg = rowptr[i], end = rowptr[i + 1];
            for (int k = beg; k < end; k++) {
                int s = csr_src[k];
                if ((rbOld[s >> 5] >> (s & 31)) & 1u) { reached = true; dist[i] = h; break; }
            }
        }
    }
    u64 b = __ballot(reached);
    if (lane == 0 && (i & ~63) < n) rbNew[i >> 6] = b;
}

// ---------------- CSR build: locality-binned 2-level counting sort (391 bins) -------
__global__ void k_bincount(const int4* __restrict__ dst4, int* bincnt, int E4) {
    __shared__ int cnt[512];
    int t = threadIdx.x;
    cnt[t] = 0; cnt[t + 256] = 0;
    __syncthreads();
    int i = blockIdx.x * 256 + t;
    if (i < E4) {
        int4 d = dst4[i];
        atomicAdd(&cnt[d.x >> NSB], 1);
        atomicAdd(&cnt[d.y >> NSB], 1);
        atomicAdd(&cnt[d.z >> NSB], 1);
        atomicAdd(&cnt[d.w >> NSB], 1);
    }
    __syncthreads();
    if (cnt[t] > 0) atomicAdd(&bincnt[t], cnt[t]);
    if (cnt[t + 256] > 0) atomicAdd(&bincnt[t + 256], cnt[t + 256]);
}

__global__ void k_binscan(const int* __restrict__ bincnt, int* binbase, int* bincur,
                          int* rowptr, int BINS, int E, int n) {
    __shared__ int sd[512];
    int t = threadIdx.x;  // 512 threads
    int v = (t < BINS) ? bincnt[t] : 0;
    sd[t] = v;
    __syncthreads();
    for (int off = 1; off < 512; off <<= 1) {
        int add = (t >= off) ? sd[t - off] : 0;
        __syncthreads();
        sd[t] += add;
        __syncthreads();
    }
    int excl = sd[t] - v;
    if (t < BINS) { binbase[t] = excl; bincur[t] = excl; }
    if (t == 0) { binbase[BINS] = E; rowptr[n] = E; }
}

__global__ void k_binscatter(const int4* __restrict__ src4, const int4* __restrict__ dst4,
                             int* bincur, int* __restrict__ pairs, int E4, int BINS) {
    __shared__ int cnt[512], base[512];
    int t = threadIdx.x;
    cnt[t] = 0; cnt[t + 256] = 0;
    __syncthreads();
    int i = blockIdx.x * 256 + t;
    int bin[4], rank[4], pack[4];
    bool valid = i < E4;
    if (valid) {
        int4 s = src4[i], d = dst4[i];
        bin[0] = d.x >> NSB; pack[0] = ((d.x & (NS - 1)) << SRCBITS) | s.x;
        bin[1] = d.y >> NSB; pack[1] = ((d.y & (NS - 1)) << SRCBITS) | s.y;
        bin[2] = d.z >> NSB; pack[2] = ((d.z & (NS - 1)) << SRCBITS) | s.z;
        bin[3] = d.w >> NSB; pack[3] = ((d.w & (NS - 1)) << SRCBITS) | s.w;
        rank[0] = atomicAdd(&cnt[bin[0]], 1);
        rank[1] = atomicAdd(&cnt[bin[1]], 1);
        rank[2] = atomicAdd(&cnt[bin[2]], 1);
        rank[3] = atomicAdd(&cnt[bin[3]], 1);
    }
    __syncthreads();
    if (cnt[t] > 0) base[t] = atomicAdd(&bincur[t], cnt[t]);
    if (cnt[t + 256] > 0) base[t + 256] = atomicAdd(&bincur[t + 256], cnt[t + 256]);
    __syncthreads();
    if (valid) {
        pairs[base[bin[0]] + rank[0]] = pack[0];
        pairs[base[bin[1]] + rank[1]] = pack[1];
        pairs[base[bin[2]] + rank[2]] = pack[2];
        pairs[base[bin[3]] + rank[3]] = pack[3];
    }
}

__global__ void k_binsort(const int* __restrict__ pairs, const int* __restrict__ binbase,
                          int* __restrict__ rowptr, int* __restrict__ csr_src, int n) {
    __shared__ int hist[NS];  // NS = 256
    const int b = blockIdx.x, t = threadIdx.x;
    const int nbeg = b << NSB;
    const int ebeg = binbase[b];
    const int ecnt = binbase[b + 1] - ebeg;
    hist[t] = 0;
    __syncthreads();
    for (int i = t; i < ecnt; i += 256)
        atomicAdd(&hist[(u32)pairs[ebeg + i] >> SRCBITS], 1);
    for (int d = 1; d < NS; d <<= 1) {
        __syncthreads();
        int idx = (t + 1) * (d << 1) - 1;
        if (idx < NS) hist[idx] += hist[idx - d];
    }
    __syncthreads();
    if (t == 0) hist[NS - 1] = 0;
    for (int d = NS / 2; d >= 1; d >>= 1) {
        __syncthreads();
        int idx = (t + 1) * (d << 1) - 1;
        if (idx < NS) { int tmp = hist[idx - d]; hist[idx - d] = hist[idx]; hist[idx] += tmp; }
    }
    __syncthreads();
    int g0 = nbeg + t;
    if (g0 < n) rowptr[g0] = ebeg + hist[t];
    __syncthreads();
    for (int i = t; i < ecnt; i += 256) {
        int p = pairs[ebeg + i];
        int pos = atomicAdd(&hist[(u32)p >> SRCBITS], 1);
        csr_src[ebeg + pos] = p & SRCMASK;
    }
}

// ---------------- layer-1 MFMA GEMM: fp32 A converted to bf16 in LDS, AUG epilogue ----
template <int SK, int MBW>
__launch_bounds__(256)
__global__ void k_gemm_mfma1(const float* __restrict__ A, const float* __restrict__ W,
                             const float* __restrict__ a_s, const float* __restrict__ a_d,
                             const int* __restrict__ dist, __half* __restrict__ out,
                             float* __restrict__ als, float* __restrict__ ald, int n) {
    constexpr int K = 128, NREAL = 64, NTT = 5, AH = 8, C = 8;
    constexpr int KT = K / 32;
    constexpr int NTCOL = (NTT - 1) * 16;
    __shared__ u16 WT[NTT * 16 * SK];
    __shared__ u16 sAW[4][16 * SK];
    __shared__ float sAug[4][64];
    __shared__ float sAugA[4][16];

    for (int idx = threadIdx.x; idx < NTT * 16 * K; idx += 256) {
        int c = idx / K, k = idx % K;
        float v;
        if (c < NREAL) {
            v = W[k * NREAL + c];
        } else {
            int j = (c - NTCOL) & 7;
            const float* aw = (c < NTCOL + AH) ? a_s : a_d;
            float accv = 0.0f;
            for (int cc = 0; cc < C; cc++) accv += W[k * NREAL + j * C + cc] * aw[j * C + cc];
            v = accv * LOG2E;
        }
        WT[c * SK + k] = f2bf(v);
    }
    {
        int t = threadIdx.x;
        int d = t >> 6, c = t & 63;
        sAug[d][c] = W[(K + d) * NREAL + c];
        if (t < 64) {
            int dd = t >> 4, j = t & 15;
            int hh = j & 7;
            const float* aw = (j < 8) ? a_s : a_d;
            float accv = 0.0f;
            for (int cc = 0; cc < C; cc++)
                accv += W[(K + dd) * NREAL + hh * C + cc] * aw[hh * C + cc];
            sAugA[dd][j] = accv * LOG2E;
        }
    }
    __syncthreads();

    const int lane = threadIdx.x & 63;
    const int l15 = lane & 15;
    const int kg = lane >> 4;
    const int w = threadIdx.x >> 6;
    const int wid = blockIdx.x * 4 + w;

    bf16x8 bfr[NTT][KT];
#pragma unroll
    for (int nt = 0; nt < NTT; nt++)
#pragma unroll
        for (int kt = 0; kt < KT; kt++)
            bfr[nt][kt] = *(const bf16x8*)&WT[(nt * 16 + l15) * SK + kt * 32 + kg * 8];

    for (int mb = 0; mb < MBW; mb++) {
        const int rowbase = (wid * MBW + mb) * 16;
        if (rowbase >= n) break;
        {
            int r = lane >> 2, c4b = lane & 3;
            const float* xr = A + (size_t)(rowbase + r) * K;
#pragma unroll
            for (int j = 0; j < 8; j++) {
                int c4 = c4b + j * 4;
                float4 v = *(const float4*)&xr[c4 * 4];
                ushort4 o;
                o.x = f2bf(v.x); o.y = f2bf(v.y); o.z = f2bf(v.z); o.w = f2bf(v.w);
                *(ushort4*)&sAW[w][r * SK + c4 * 4] = o;
            }
        }
        bf16x8 af[KT];
#pragma unroll
        for (int kt = 0; kt < KT; kt++)
            af[kt] = *(const bf16x8*)&sAW[w][l15 * SK + kt * 32 + kg * 8];
        f32x4 acc[NTT];
#pragma unroll
        for (int nt = 0; nt < NTT; nt++) acc[nt] = f32x4{0.f, 0.f, 0.f, 0.f};
#pragma unroll
        for (int kt = 0; kt < KT; kt++)
#pragma unroll
            for (int nt = 0; nt < NTT; nt++)
                acc[nt] = __builtin_amdgcn_mfma_f32_16x16x32_bf16(af[kt], bfr[nt][kt],
                                                                  acc[nt], 0, 0, 0);
        int rows[4], dd[4];
#pragma unroll
        for (int r = 0; r < 4; r++) {
            rows[r] = rowbase + kg * 4 + r;
            dd[r] = dist[rows[r]];
        }
#pragma unroll
        for (int nt = 0; nt < NTT - 1; nt++) {
            int c = nt * 16 + l15;
#pragma unroll
            for (int r = 0; r < 4; r++) {
                float v = acc[nt][r];
                if (dd[r] <= MAXH) v += sAug[dd[r]][c];
                out[(size_t)rows[r] * NREAL + c] = __float2half(v);
            }
        }
#pragma unroll
        for (int r = 0; r < 4; r++) {
            float v = acc[NTT - 1][r];
            if (dd[r] <= MAXH) v += sAugA[dd[r]][l15];
            if (l15 < AH) als[(size_t)rows[r] * AH + l15] = v;
            else ald[(size_t)rows[r] * AH + (l15 - AH)] = v;
        }
    }
}

// ---------------- MFMA GEMM (A bf16) with fused attn-logit columns ----------------
template <int K, int NREAL, int NTT, int AH, int C, int SK, int MBW>
__launch_bounds__(256)
__global__ void k_gemm_mfma(const u16* __restrict__ A, const float* __restrict__ W,
                            const float* __restrict__ a_s, const float* __restrict__ a_d,
                            __half* __restrict__ out, float* __restrict__ als,
                            float* __restrict__ ald, int n) {
    constexpr int KT = K / 32;
    constexpr int NTCOL = (NTT - 1) * 16;
    __shared__ u16 WT[NTT * 16 * SK];
    for (int idx = threadIdx.x; idx < NTT * 16 * K; idx += 256) {
        int c = idx / K, k = idx % K;
        float v = 0.0f;
        if (c < NREAL) {
            v = W[k * NREAL + c];
        } else if (c >= NTCOL && c < NTCOL + 2 * AH) {
            int j = (c - NTCOL) % AH;
            const float* aw = (c < NTCOL + AH) ? a_s : a_d;
            float accv = 0.0f;
            for (int cc = 0; cc < C; cc++) accv += W[k * NREAL + j * C + cc] * aw[j * C + cc];
            v = accv * LOG2E;
        }
        WT[c * SK + k] = f2bf(v);
    }
    __syncthreads();

    const int lane = threadIdx.x & 63;
    const int l15 = lane & 15;
    const int kg = lane >> 4;
    const int wid = blockIdx.x * 4 + (threadIdx.x >> 6);

    bf16x8 bfr[NTT][KT];
#pragma unroll
    for (int nt = 0; nt < NTT; nt++)
#pragma unroll
        for (int kt = 0; kt < KT; kt++)
            bfr[nt][kt] = *(const bf16x8*)&WT[(nt * 16 + l15) * SK + kt * 32 + kg * 8];

    for (int mb = 0; mb < MBW; mb++) {
        const int rowbase = (wid * MBW + mb) * 16;
        if (rowbase >= n) break;
        bf16x8 af[KT];
#pragma unroll
        for (int kt = 0; kt < KT; kt++)
            af[kt] = *(const bf16x8*)&A[(size_t)(rowbase + l15) * K + kt * 32 + kg * 8];
        f32x4 acc[NTT];
#pragma unroll
        for (int nt = 0; nt < NTT; nt++) acc[nt] = f32x4{0.f, 0.f, 0.f, 0.f};
#pragma unroll
        for (int kt = 0; kt < KT; kt++)
#pragma unroll
            for (int nt = 0; nt < NTT; nt++)
                acc[nt] = __builtin_amdgcn_mfma_f32_16x16x32_bf16(af[kt], bfr[nt][kt],
                                                                  acc[nt], 0, 0, 0);
#pragma unroll
        for (int nt = 0; nt < NTT - 1; nt++) {
            int c = nt * 16 + l15;
            if (c < NREAL) {
#pragma unroll
                for (int r = 0; r < 4; r++) {
                    int row = rowbase + kg * 4 + r;
                    out[(size_t)row * NREAL + c] = __float2half(acc[nt][r]);
                }
            }
        }
#pragma unroll
        for (int r = 0; r < 4; r++) {
            int row = rowbase + kg * 4 + r;
            float v = acc[NTT - 1][r];
            if (l15 < AH) als[(size_t)row * AH + l15] = v;
            else if (l15 < 2 * AH) ald[(size_t)row * AH + (l15 - AH)] = v;
        }
    }
}

// ---------------- fused GAT (round-8 form), 1024-thread blocks for occupancy ----
template <int H, int C, int CH, int MODE, typename OT>
__launch_bounds__(1024)
__global__ void k_gat(const int* __restrict__ rowptr, const int* __restrict__ csr_src,
                      const __half* __restrict__ h, const float* __restrict__ als,
                      const float* __restrict__ ald, const float* __restrict__ bias,
                      const int* __restrict__ dist, const float* __restrict__ Wg,
                      const float* __restrict__ bg, OT* __restrict__ out, int n) {
    constexpr int TOT = H * C;
    constexpr int NL = TOT / CH;
    const int lane = threadIdx.x & 63;
    const int node = blockIdx.x * 16 + (threadIdx.x >> 6);
    if (node >= n) return;
    const int beg = rowptr[node];
    const int deg = rowptr[node + 1] - beg;

    const int cl = (lane < NL) ? lane : 0;
    const int hd = (cl * CH) / C;
    const float ald_hd = ald[(size_t)node * H + hd];
    const float t0 = als[(size_t)node * H + hd] + ald_hd;
    const float m0 = fmaxf(t0, 0.2f * t0);
    const float c0 = ald_hd - m0;
    const float c1 = 0.2f * ald_hd - m0;

    float s = 1.0f;
    float ax = 0.0f, ay = 0.0f;
    __half2 acc2;
    if (MODE == 2) {
        acc2 = *(const __half2*)(h + (size_t)node * TOT + cl * 2);  // self, weight 1
    } else {
        ax = __half2float(h[(size_t)node * TOT + cl]);
    }

    auto body = [&](int sN) {
        float a = als[(size_t)sN * H + hd];
        float v = fmaxf(a + c0, fmaf(a, 0.2f, c1));
        float p = fexp2(v);
        s += p;
        if (MODE == 2) {
            __half2 ph = __float2half2_rn(p);
            acc2 = __hfma2(ph, *(const __half2*)(h + (size_t)sN * TOT + cl * 2), acc2);
        } else {
            ax += p * __half2float(h[(size_t)sN * TOT + cl]);
        }
    };

    for (int base = 0; base < deg; base += 64) {
        const int myE = base + lane;
        int sReg = (myE < deg) ? csr_src[beg + myE] : 0;
        const int cnt = min(64, deg - base);
        int e = 0;
        for (; e + 4 <= cnt; e += 4) {
            body(__builtin_amdgcn_readlane(sReg, e));
            body(__builtin_amdgcn_readlane(sReg, e + 1));
            body(__builtin_amdgcn_readlane(sReg, e + 2));
            body(__builtin_amdgcn_readlane(sReg, e + 3));
        }
        for (; e < cnt; e++) body(__builtin_amdgcn_readlane(sReg, e));
    }

    const float inv = 1.0f / (s + 1e-16f);
    if (MODE == 2) {
        float2 av = __half22float2(acc2);
        ax = av.x; ay = av.y;
    }
    float vx = ax * inv + bias[cl * CH];
    float vy = (CH == 2) ? (ay * inv + bias[cl * CH + 1]) : 0.0f;

    if (MODE == 1) {  // ELU -> bf16
        vx = vx > 0.0f ? vx : expm1f(vx);
        ((u16*)out)[(size_t)node * TOT + cl] = f2bf(vx);
    } else if (MODE == 2) {  // gate -> bf16
        float2 wg = *(const float2*)&Wg[cl * 2];
        float part = vx * wg.x + vy * wg.y;
#pragma unroll
        for (int off = 32; off > 0; off >>= 1) part += __shfl_xor(part, off);
        int d = dist[node];
        float hop = (d <= MAXH) ? (float)d : 0.0f;
        float g = 1.0f / (1.0f + __expf(-(part + hop * Wg[128] + bg[0])));
        ushort2 wv;
        wv.x = f2bf(vx * g);
        wv.y = f2bf(vy * g);
        *(ushort2*)&((u16*)out)[(size_t)node * TOT + cl * 2] = wv;
    } else if (MODE == 3) {  // log_softmax -> fp32
        float v = (lane < NL) ? vx : -INFINITY;
        float mm = v;
#pragma unroll
        for (int off = 32; off > 0; off >>= 1) mm = fmaxf(mm, __shfl_xor(mm, off));
        float ex = (lane < NL) ? __expf(v - mm) : 0.0f;
        float ss = ex;
#pragma unroll
        for (int off = 32; off > 0; off >>= 1) ss += __shfl_xor(ss, off);
        float ls = logf(ss);
        if (lane < NL) ((float*)out)[(size_t)node * TOT + cl] = v - mm - ls;
    }
}

static inline int nblk(long long t, int b) { return (int)((t + b - 1) / b); }

extern "C" void kernel_launch(void* const* d_in, const int* in_sizes, int n_in,
                              void* d_out, int out_size, void* d_ws, size_t ws_size,
                              hipStream_t stream) {
    const float* x = (const float*)d_in[0];
    const int* eidx = (const int*)d_in[1];
    const int* seed_mask = (const int*)d_in[2];
    const float* W1 = (const float*)d_in[3];
    const float* a1s = (const float*)d_in[4];
    const float* a1d = (const float*)d_in[5];
    const float* b1 = (const float*)d_in[6];
    const float* W2 = (const float*)d_in[7];
    const float* a2s = (const float*)d_in[8];
    const float* a2d = (const float*)d_in[9];
    const float* b2 = (const float*)d_in[10];
    const float* W3 = (const float*)d_in[11];
    const float* a3s = (const float*)d_in[12];
    const float* a3d = (const float*)d_in[13];
    const float* b3 = (const float*)d_in[14];
    const float* Wg = (const float*)d_in[15];
    const float* bg = (const float*)d_in[16];

    const int n = in_sizes[0] / 128;        // 100000
    const long long E = in_sizes[1] / 2;    // 1600000
    const int E4 = (int)(E / 4);
    const int4* src4 = (const int4*)eidx;
    const int4* dst4 = (const int4*)(eidx + E);
    const int BINS = (n + NS - 1) >> NSB;   // 391 <= 512
    const int NW64 = (n + 63) / 64;

    char* ws = (char*)d_ws;
    size_t off = 0;
    auto alloc = [&](size_t bytes) -> void* {
        void* p = ws + off;
        off = (off + bytes + 255) & ~(size_t)255;
        return p;
    };
    int* dist    = (int*)alloc((size_t)n * 4);
    u64* rbA     = (u64*)alloc((size_t)NW64 * 8);
    u64* rbB     = (u64*)alloc((size_t)NW64 * 8);
    int* rowptr  = (int*)alloc((size_t)(n + 1) * 4);
    int* bincnt  = (int*)alloc(512 * 4);
    int* binbase = (int*)alloc(513 * 4);
    int* bincur  = (int*)alloc(512 * 4);
    int* csr_src = (int*)alloc((size_t)E * 4);
    float* als   = (float*)alloc((size_t)n * 8 * 4);
    float* ald   = (float*)alloc((size_t)n * 8 * 4);
    __half* hbuf = (__half*)alloc((size_t)n * 128 * 2);  // GEMM out (h), fp16
    u16* abuf    = (u16*)alloc((size_t)n * 128 * 2);     // GAT out (next GEMM A), bf16
    int* pairs   = (int*)abuf;  // alias: pairs only live during CSR build
    float* out = (float*)d_out;

    const int BS = 256;

    // ---- init (dist + seed bitset + bincnt zero) ----
    k_init<<<nblk(n, BS), BS, 0, stream>>>(seed_mask, dist, rbA, bincnt, n);

    // ---- CSR build: binned counting sort ----
    k_bincount<<<nblk(E4, BS), BS, 0, stream>>>(dst4, bincnt, E4);
    k_binscan<<<1, 512, 0, stream>>>(bincnt, binbase, bincur, rowptr, BINS, (int)E, n);
    k_binscatter<<<nblk(E4, BS), BS, 0, stream>>>(src4, dst4, bincur, pairs, E4, BINS);
    k_binsort<<<BINS, 256, 0, stream>>>(pairs, binbase, rowptr, csr_src, n);

    // ---- BFS hierarchy (double-buffered bitset, fused scan+update) ----
    k_bfs_step<<<nblk(n, BS), BS, 0, stream>>>(rowptr, csr_src, (const u32*)rbA, rbB,
                                               dist, 1, n);
    k_bfs_step<<<nblk(n, BS), BS, 0, stream>>>(rowptr, csr_src, (const u32*)rbB, rbA,
                                               dist, 2, n);
    k_bfs_step<<<nblk(n, BS), BS, 0, stream>>>(rowptr, csr_src, (const u32*)rbA, rbB,
                                               dist, 3, n);

    const int mblocks = (n + 15) / 16;
    const int gmf = (mblocks + 15) / 16;   // 4 waves x MBW=4 m-blocks per block

    // ---- Layer 1: aug(132) -> 8x8, ELU fused (MFMA, x converted to bf16 in LDS) ----
    k_gemm_mfma1<136, 4>
        <<<gmf, 256, 0, stream>>>(x, W1, a1s, a1d, dist, hbuf, als, ald, n);
    k_gat<8, 8, 1, 1, u16><<<nblk(n, 16), 1024, 0, stream>>>(
        rowptr, csr_src, hbuf, als, ald, b1, nullptr, nullptr, nullptr, abuf, n);

    // ---- Layer 2: 64 -> 8x16, gate fused (MFMA GEMM, bf16 A) ----
    k_gemm_mfma<64, 128, 9, 8, 16, 72, 4>
        <<<gmf, 256, 0, stream>>>(abuf, W2, a2s, a2d, hbuf, als, ald, n);
    k_gat<8, 16, 2, 2, u16><<<nblk(n, 16), 1024, 0, stream>>>(
        rowptr, csr_src, hbuf, als, ald, b2, dist, Wg, bg, abuf, n);

    // ---- Layer 3: 128 -> 1x40, log_softmax fused (MFMA GEMM, bf16 A) ----
    k_gemm_mfma<128, 40, 4, 1, 40, 136, 4>
        <<<gmf, 256, 0, stream>>>(abuf, W3, a3s, a3d, hbuf, als, ald, n);
    k_gat<1, 40, 1, 3, float><<<nblk(n, 16), 1024, 0, stream>>>(
        rowptr, csr_src, hbuf, als, ald, b3, nullptr, nullptr, nullptr, out, n);
}

// Round 14
// 422.610 us; speedup vs baseline: 1.0447x; 1.0447x over previous
//
#include <hip/hip_runtime.h>
#include <hip/hip_bf16.h>
#include <hip/hip_fp16.h>
#include <math.h>

#define MAXH 3
#define NSB 8              // 256 nodes per bin
#define NS (1 << NSB)
#define SRCBITS 17         // n < 131072
#define SRCMASK ((1 << SRCBITS) - 1)
#define LOG2E 1.4426950408889634f
typedef unsigned int u32;
typedef unsigned long long u64;
typedef unsigned char u8;
typedef unsigned short u16;

using bf16x8 = __attribute__((ext_vector_type(8))) short;
using f32x4  = __attribute__((ext_vector_type(4))) float;

__device__ __forceinline__ float fexp2(float x) {
#if __has_builtin(__builtin_amdgcn_exp2f)
    return __builtin_amdgcn_exp2f(x);
#else
    return exp2f(x);
#endif
}
__device__ __forceinline__ u16 f2bf(float f) {  // RNE float->bf16
    u32 u = __float_as_uint(f);
    u32 r = ((u >> 16) & 1u) + 0x7fffu;
    return (u16)((u + r) >> 16);
}

// ---------------- fused init: dist + reached bitset (ballot) + bincnt zero ----------
__global__ void k_init(const int* __restrict__ seed_mask, int* dist, u64* rb64,
                       int* bincnt, int n) {
    int i = blockIdx.x * 256 + threadIdx.x;
    int lane = threadIdx.x & 63;
    bool seed = (i < n) && (seed_mask[i] == 0);
    if (i < n) dist[i] = seed ? 0 : (MAXH + 1);
    u64 b = __ballot(seed);
    if (lane == 0 && (i & ~63) < n) rb64[i >> 6] = b;
    if (blockIdx.x == 0) {
        bincnt[threadIdx.x] = 0;
        bincnt[threadIdx.x + 256] = 0;
    }
}

// ---------------- BFS step: scan in-neighbors (old bitset) -> new bitset + dist -----
__global__ void k_bfs_step(const int* __restrict__ rowptr, const int* __restrict__ csr_src,
                           const u32* __restrict__ rbOld, u64* rbNew, int* dist,
                           int h, int n) {
    int i = blockIdx.x * 256 + threadIdx.x;
    int lane = threadIdx.x & 63;
    bool reached = false;
    if (i < n) {
        reached = (rbOld[i >> 5] >> (i & 31)) & 1u;
        if (!reached) {
            int beg = rowptr[i], end = rowptr[i + 1];
            for (int k = beg; k < end; k++) {
                int s = csr_src[k];
                if ((rbOld[s >> 5] >> (s & 31)) & 1u) { reached = true; dist[i] = h; break; }
            }
        }
    }
    u64 b = __ballot(reached);
    if (lane == 0 && (i & ~63) < n) rbNew[i >> 6] = b;
}

// ---------------- CSR build: locality-binned 2-level counting sort (391 bins) -------
__global__ void k_bincount(const int4* __restrict__ dst4, int* bincnt, int E4) {
    __shared__ int cnt[512];
    int t = threadIdx.x;
    cnt[t] = 0; cnt[t + 256] = 0;
    __syncthreads();
    int i = blockIdx.x * 256 + t;
    if (i < E4) {
        int4 d = dst4[i];
        atomicAdd(&cnt[d.x >> NSB], 1);
        atomicAdd(&cnt[d.y >> NSB], 1);
        atomicAdd(&cnt[d.z >> NSB], 1);
        atomicAdd(&cnt[d.w >> NSB], 1);
    }
    __syncthreads();
    if (cnt[t] > 0) atomicAdd(&bincnt[t], cnt[t]);
    if (cnt[t + 256] > 0) atomicAdd(&bincnt[t + 256], cnt[t + 256]);
}

__global__ void k_binscan(const int* __restrict__ bincnt, int* binbase, int* bincur,
                          int* rowptr, int BINS, int E, int n) {
    __shared__ int sd[512];
    int t = threadIdx.x;  // 512 threads
    int v = (t < BINS) ? bincnt[t] : 0;
    sd[t] = v;
    __syncthreads();
    for (int off = 1; off < 512; off <<= 1) {
        int add = (t >= off) ? sd[t - off] : 0;
        __syncthreads();
        sd[t] += add;
        __syncthreads();
    }
    int excl = sd[t] - v;
    if (t < BINS) { binbase[t] = excl; bincur[t] = excl; }
    if (t == 0) { binbase[BINS] = E; rowptr[n] = E; }
}

__global__ void k_binscatter(const int4* __restrict__ src4, const int4* __restrict__ dst4,
                             int* bincur, int* __restrict__ pairs, int E4, int BINS) {
    __shared__ int cnt[512], base[512];
    int t = threadIdx.x;
    cnt[t] = 0; cnt[t + 256] = 0;
    __syncthreads();
    int i = blockIdx.x * 256 + t;
    int bin[4], rank[4], pack[4];
    bool valid = i < E4;
    if (valid) {
        int4 s = src4[i], d = dst4[i];
        bin[0] = d.x >> NSB; pack[0] = ((d.x & (NS - 1)) << SRCBITS) | s.x;
        bin[1] = d.y >> NSB; pack[1] = ((d.y & (NS - 1)) << SRCBITS) | s.y;
        bin[2] = d.z >> NSB; pack[2] = ((d.z & (NS - 1)) << SRCBITS) | s.z;
        bin[3] = d.w >> NSB; pack[3] = ((d.w & (NS - 1)) << SRCBITS) | s.w;
        rank[0] = atomicAdd(&cnt[bin[0]], 1);
        rank[1] = atomicAdd(&cnt[bin[1]], 1);
        rank[2] = atomicAdd(&cnt[bin[2]], 1);
        rank[3] = atomicAdd(&cnt[bin[3]], 1);
    }
    __syncthreads();
    if (cnt[t] > 0) base[t] = atomicAdd(&bincur[t], cnt[t]);
    if (cnt[t + 256] > 0) base[t + 256] = atomicAdd(&bincur[t + 256], cnt[t + 256]);
    __syncthreads();
    if (valid) {
        pairs[base[bin[0]] + rank[0]] = pack[0];
        pairs[base[bin[1]] + rank[1]] = pack[1];
        pairs[base[bin[2]] + rank[2]] = pack[2];
        pairs[base[bin[3]] + rank[3]] = pack[3];
    }
}

__global__ void k_binsort(const int* __restrict__ pairs, const int* __restrict__ binbase,
                          int* __restrict__ rowptr, int* __restrict__ csr_src, int n) {
    __shared__ int hist[NS];  // NS = 256
    const int b = blockIdx.x, t = threadIdx.x;
    const int nbeg = b << NSB;
    const int ebeg = binbase[b];
    const int ecnt = binbase[b + 1] - ebeg;
    hist[t] = 0;
    __syncthreads();
    for (int i = t; i < ecnt; i += 256)
        atomicAdd(&hist[(u32)pairs[ebeg + i] >> SRCBITS], 1);
    for (int d = 1; d < NS; d <<= 1) {
        __syncthreads();
        int idx = (t + 1) * (d << 1) - 1;
        if (idx < NS) hist[idx] += hist[idx - d];
    }
    __syncthreads();
    if (t == 0) hist[NS - 1] = 0;
    for (int d = NS / 2; d >= 1; d >>= 1) {
        __syncthreads();
        int idx = (t + 1) * (d << 1) - 1;
        if (idx < NS) { int tmp = hist[idx - d]; hist[idx - d] = hist[idx]; hist[idx] += tmp; }
    }
    __syncthreads();
    int g0 = nbeg + t;
    if (g0 < n) rowptr[g0] = ebeg + hist[t];
    __syncthreads();
    for (int i = t; i < ecnt; i += 256) {
        int p = pairs[ebeg + i];
        int pos = atomicAdd(&hist[(u32)p >> SRCBITS], 1);
        csr_src[ebeg + pos] = p & SRCMASK;
    }
}

// ---------------- layer-1 MFMA GEMM: fp32 A converted to bf16 in LDS, AUG epilogue ----
template <int SK, int MBW>
__launch_bounds__(256)
__global__ void k_gemm_mfma1(const float* __restrict__ A, const float* __restrict__ W,
                             const float* __restrict__ a_s, const float* __restrict__ a_d,
                             const int* __restrict__ dist, __half* __restrict__ out,
                             float* __restrict__ als, float* __restrict__ ald, int n) {
    constexpr int K = 128, NREAL = 64, NTT = 5, AH = 8, C = 8;
    constexpr int KT = K / 32;
    constexpr int NTCOL = (NTT - 1) * 16;
    __shared__ u16 WT[NTT * 16 * SK];
    __shared__ u16 sAW[4][16 * SK];
    __shared__ float sAug[4][64];
    __shared__ float sAugA[4][16];

    for (int idx = threadIdx.x; idx < NTT * 16 * K; idx += 256) {
        int c = idx / K, k = idx % K;
        float v;
        if (c < NREAL) {
            v = W[k * NREAL + c];
        } else {
            int j = (c - NTCOL) & 7;
            const float* aw = (c < NTCOL + AH) ? a_s : a_d;
            float accv = 0.0f;
            for (int cc = 0; cc < C; cc++) accv += W[k * NREAL + j * C + cc] * aw[j * C + cc];
            v = accv * LOG2E;
        }
        WT[c * SK + k] = f2bf(v);
    }
    {
        int t = threadIdx.x;
        int d = t >> 6, c = t & 63;
        sAug[d][c] = W[(K + d) * NREAL + c];
        if (t < 64) {
            int dd = t >> 4, j = t & 15;
            int hh = j & 7;
            const float* aw = (j < 8) ? a_s : a_d;
            float accv = 0.0f;
            for (int cc = 0; cc < C; cc++)
                accv += W[(K + dd) * NREAL + hh * C + cc] * aw[hh * C + cc];
            sAugA[dd][j] = accv * LOG2E;
        }
    }
    __syncthreads();

    const int lane = threadIdx.x & 63;
    const int l15 = lane & 15;
    const int kg = lane >> 4;
    const int w = threadIdx.x >> 6;
    const int wid = blockIdx.x * 4 + w;

    bf16x8 bfr[NTT][KT];
#pragma unroll
    for (int nt = 0; nt < NTT; nt++)
#pragma unroll
        for (int kt = 0; kt < KT; kt++)
            bfr[nt][kt] = *(const bf16x8*)&WT[(nt * 16 + l15) * SK + kt * 32 + kg * 8];

    for (int mb = 0; mb < MBW; mb++) {
        const int rowbase = (wid * MBW + mb) * 16;
        if (rowbase >= n) break;
        {
            int r = lane >> 2, c4b = lane & 3;
            const float* xr = A + (size_t)(rowbase + r) * K;
#pragma unroll
            for (int j = 0; j < 8; j++) {
                int c4 = c4b + j * 4;
                float4 v = *(const float4*)&xr[c4 * 4];
                ushort4 o;
                o.x = f2bf(v.x); o.y = f2bf(v.y); o.z = f2bf(v.z); o.w = f2bf(v.w);
                *(ushort4*)&sAW[w][r * SK + c4 * 4] = o;
            }
        }
        bf16x8 af[KT];
#pragma unroll
        for (int kt = 0; kt < KT; kt++)
            af[kt] = *(const bf16x8*)&sAW[w][l15 * SK + kt * 32 + kg * 8];
        f32x4 acc[NTT];
#pragma unroll
        for (int nt = 0; nt < NTT; nt++) acc[nt] = f32x4{0.f, 0.f, 0.f, 0.f};
#pragma unroll
        for (int kt = 0; kt < KT; kt++)
#pragma unroll
            for (int nt = 0; nt < NTT; nt++)
                acc[nt] = __builtin_amdgcn_mfma_f32_16x16x32_bf16(af[kt], bfr[nt][kt],
                                                                  acc[nt], 0, 0, 0);
        int rows[4], dd[4];
#pragma unroll
        for (int r = 0; r < 4; r++) {
            rows[r] = rowbase + kg * 4 + r;
            dd[r] = dist[rows[r]];
        }
#pragma unroll
        for (int nt = 0; nt < NTT - 1; nt++) {
            int c = nt * 16 + l15;
#pragma unroll
            for (int r = 0; r < 4; r++) {
                float v = acc[nt][r];
                if (dd[r] <= MAXH) v += sAug[dd[r]][c];
                out[(size_t)rows[r] * NREAL + c] = __float2half(v);
            }
        }
#pragma unroll
        for (int r = 0; r < 4; r++) {
            float v = acc[NTT - 1][r];
            if (dd[r] <= MAXH) v += sAugA[dd[r]][l15];
            if (l15 < AH) als[(size_t)rows[r] * AH + l15] = v;
            else ald[(size_t)rows[r] * AH + (l15 - AH)] = v;
        }
    }
}

// ---------------- MFMA GEMM (A bf16) with fused attn-logit columns ----------------
template <int K, int NREAL, int NTT, int AH, int C, int SK, int MBW>
__launch_bounds__(256)
__global__ void k_gemm_mfma(const u16* __restrict__ A, const float* __restrict__ W,
                            const float* __restrict__ a_s, const float* __restrict__ a_d,
                            __half* __restrict__ out, float* __restrict__ als,
                            float* __restrict__ ald, int n) {
    constexpr int KT = K / 32;
    constexpr int NTCOL = (NTT - 1) * 16;
    __shared__ u16 WT[NTT * 16 * SK];
    for (int idx = threadIdx.x; idx < NTT * 16 * K; idx += 256) {
        int c = idx / K, k = idx % K;
        float v = 0.0f;
        if (c < NREAL) {
            v = W[k * NREAL + c];
        } else if (c >= NTCOL && c < NTCOL + 2 * AH) {
            int j = (c - NTCOL) % AH;
            const float* aw = (c < NTCOL + AH) ? a_s : a_d;
            float accv = 0.0f;
            for (int cc = 0; cc < C; cc++) accv += W[k * NREAL + j * C + cc] * aw[j * C + cc];
            v = accv * LOG2E;
        }
        WT[c * SK + k] = f2bf(v);
    }
    __syncthreads();

    const int lane = threadIdx.x & 63;
    const int l15 = lane & 15;
    const int kg = lane >> 4;
    const int wid = blockIdx.x * 4 + (threadIdx.x >> 6);

    bf16x8 bfr[NTT][KT];
#pragma unroll
    for (int nt = 0; nt < NTT; nt++)
#pragma unroll
        for (int kt = 0; kt < KT; kt++)
            bfr[nt][kt] = *(const bf16x8*)&WT[(nt * 16 + l15) * SK + kt * 32 + kg * 8];

    for (int mb = 0; mb < MBW; mb++) {
        const int rowbase = (wid * MBW + mb) * 16;
        if (rowbase >= n) break;
        bf16x8 af[KT];
#pragma unroll
        for (int kt = 0; kt < KT; kt++)
            af[kt] = *(const bf16x8*)&A[(size_t)(rowbase + l15) * K + kt * 32 + kg * 8];
        f32x4 acc[NTT];
#pragma unroll
        for (int nt = 0; nt < NTT; nt++) acc[nt] = f32x4{0.f, 0.f, 0.f, 0.f};
#pragma unroll
        for (int kt = 0; kt < KT; kt++)
#pragma unroll
            for (int nt = 0; nt < NTT; nt++)
                acc[nt] = __builtin_amdgcn_mfma_f32_16x16x32_bf16(af[kt], bfr[nt][kt],
                                                                  acc[nt], 0, 0, 0);
#pragma unroll
        for (int nt = 0; nt < NTT - 1; nt++) {
            int c = nt * 16 + l15;
            if (c < NREAL) {
#pragma unroll
                for (int r = 0; r < 4; r++) {
                    int row = rowbase + kg * 4 + r;
                    out[(size_t)row * NREAL + c] = __float2half(acc[nt][r]);
                }
            }
        }
#pragma unroll
        for (int r = 0; r < 4; r++) {
            int row = rowbase + kg * 4 + r;
            float v = acc[NTT - 1][r];
            if (l15 < AH) als[(size_t)row * AH + l15] = v;
            else if (l15 < 2 * AH) ald[(size_t)row * AH + (l15 - AH)] = v;
        }
    }
}

// ---------------- fused GAT: 256-thread blocks, 8 waves/EU, dual accumulator chains --
template <int H, int C, int CH, int MODE, typename OT>
__launch_bounds__(256, 8)
__global__ void k_gat(const int* __restrict__ rowptr, const int* __restrict__ csr_src,
                      const __half* __restrict__ h, const float* __restrict__ als,
                      const float* __restrict__ ald, const float* __restrict__ bias,
                      const int* __restrict__ dist, const float* __restrict__ Wg,
                      const float* __restrict__ bg, OT* __restrict__ out, int n) {
    constexpr int TOT = H * C;
    constexpr int NL = TOT / CH;
    const int lane = threadIdx.x & 63;
    const int node = blockIdx.x * 4 + (threadIdx.x >> 6);
    if (node >= n) return;
    const int beg = rowptr[node];
    const int deg = rowptr[node + 1] - beg;

    const int cl = (lane < NL) ? lane : 0;
    const int hd = (cl * CH) / C;
    const float ald_hd = ald[(size_t)node * H + hd];
    const float t0 = als[(size_t)node * H + hd] + ald_hd;
    const float m0 = fmaxf(t0, 0.2f * t0);
    const float c0 = ald_hd - m0;
    const float c1 = 0.2f * ald_hd - m0;

    // dual accumulator chains (A = self-initialized, B = zero)
    float sA = 1.0f, sB = 0.0f;
    float axA = 0.0f, axB = 0.0f;
    __half2 accA, accB;
    if (MODE == 2) {
        accA = *(const __half2*)(h + (size_t)node * TOT + cl * 2);  // self, weight 1
        accB = __floats2half2_rn(0.0f, 0.0f);
    } else {
        axA = __half2float(h[(size_t)node * TOT + cl]);
    }

    auto body = [&](int sN, float& s, float& ax, __half2& acc2) {
        float a = als[(size_t)sN * H + hd];
        float v = fmaxf(a + c0, fmaf(a, 0.2f, c1));
        float p = fexp2(v);
        s += p;
        if (MODE == 2) {
            __half2 ph = __float2half2_rn(p);
            acc2 = __hfma2(ph, *(const __half2*)(h + (size_t)sN * TOT + cl * 2), acc2);
        } else {
            ax += p * __half2float(h[(size_t)sN * TOT + cl]);
        }
    };

    for (int base = 0; base < deg; base += 64) {
        const int myE = base + lane;
        int sReg = (myE < deg) ? csr_src[beg + myE] : 0;
        const int cnt = min(64, deg - base);
        int e = 0;
        for (; e + 4 <= cnt; e += 4) {
            body(__builtin_amdgcn_readlane(sReg, e), sA, axA, accA);
            body(__builtin_amdgcn_readlane(sReg, e + 1), sB, axB, accB);
            body(__builtin_amdgcn_readlane(sReg, e + 2), sA, axA, accA);
            body(__builtin_amdgcn_readlane(sReg, e + 3), sB, axB, accB);
        }
        for (; e < cnt; e++) body(__builtin_amdgcn_readlane(sReg, e), sA, axA, accA);
    }

    float s = sA + sB;
    const float inv = 1.0f / (s + 1e-16f);
    float ax, ay = 0.0f;
    if (MODE == 2) {
        float2 avA = __half22float2(accA);
        float2 avB = __half22float2(accB);
        ax = avA.x + avB.x;
        ay = avA.y + avB.y;
    } else {
        ax = axA + axB;
    }
    float vx = ax * inv + bias[cl * CH];
    float vy = (CH == 2) ? (ay * inv + bias[cl * CH + 1]) : 0.0f;

    if (MODE == 1) {  // ELU -> bf16
        vx = vx > 0.0f ? vx : expm1f(vx);
        ((u16*)out)[(size_t)node * TOT + cl] = f2bf(vx);
    } else if (MODE == 2) {  // gate -> bf16
        float2 wg = *(const float2*)&Wg[cl * 2];
        float part = vx * wg.x + vy * wg.y;
#pragma unroll
        for (int off = 32; off > 0; off >>= 1) part += __shfl_xor(part, off);
        int d = dist[node];
        float hop = (d <= MAXH) ? (float)d : 0.0f;
        float g = 1.0f / (1.0f + __expf(-(part + hop * Wg[128] + bg[0])));
        ushort2 wv;
        wv.x = f2bf(vx * g);
        wv.y = f2bf(vy * g);
        *(ushort2*)&((u16*)out)[(size_t)node * TOT + cl * 2] = wv;
    } else if (MODE == 3) {  // log_softmax -> fp32
        float v = (lane < NL) ? vx : -INFINITY;
        float mm = v;
#pragma unroll
        for (int off = 32; off > 0; off >>= 1) mm = fmaxf(mm, __shfl_xor(mm, off));
        float ex = (lane < NL) ? __expf(v - mm) : 0.0f;
        float ss = ex;
#pragma unroll
        for (int off = 32; off > 0; off >>= 1) ss += __shfl_xor(ss, off);
        float ls = logf(ss);
        if (lane < NL) ((float*)out)[(size_t)node * TOT + cl] = v - mm - ls;
    }
}

static inline int nblk(long long t, int b) { return (int)((t + b - 1) / b); }

extern "C" void kernel_launch(void* const* d_in, const int* in_sizes, int n_in,
                              void* d_out, int out_size, void* d_ws, size_t ws_size,
                              hipStream_t stream) {
    const float* x = (const float*)d_in[0];
    const int* eidx = (const int*)d_in[1];
    const int* seed_mask = (const int*)d_in[2];
    const float* W1 = (const float*)d_in[3];
    const float* a1s = (const float*)d_in[4];
    const float* a1d = (const float*)d_in[5];
    const float* b1 = (const float*)d_in[6];
    const float* W2 = (const float*)d_in[7];
    const float* a2s = (const float*)d_in[8];
    const float* a2d = (const float*)d_in[9];
    const float* b2 = (const float*)d_in[10];
    const float* W3 = (const float*)d_in[11];
    const float* a3s = (const float*)d_in[12];
    const float* a3d = (const float*)d_in[13];
    const float* b3 = (const float*)d_in[14];
    const float* Wg = (const float*)d_in[15];
    const float* bg = (const float*)d_in[16];

    const int n = in_sizes[0] / 128;        // 100000
    const long long E = in_sizes[1] / 2;    // 1600000
    const int E4 = (int)(E / 4);
    const int4* src4 = (const int4*)eidx;
    const int4* dst4 = (const int4*)(eidx + E);
    const int BINS = (n + NS - 1) >> NSB;   // 391 <= 512
    const int NW64 = (n + 63) / 64;

    char* ws = (char*)d_ws;
    size_t off = 0;
    auto alloc = [&](size_t bytes) -> void* {
        void* p = ws + off;
        off = (off + bytes + 255) & ~(size_t)255;
        return p;
    };
    int* dist    = (int*)alloc((size_t)n * 4);
    u64* rbA     = (u64*)alloc((size_t)NW64 * 8);
    u64* rbB     = (u64*)alloc((size_t)NW64 * 8);
    int* rowptr  = (int*)alloc((size_t)(n + 1) * 4);
    int* bincnt  = (int*)alloc(512 * 4);
    int* binbase = (int*)alloc(513 * 4);
    int* bincur  = (int*)alloc(512 * 4);
    int* csr_src = (int*)alloc((size_t)E * 4);
    float* als   = (float*)alloc((size_t)n * 8 * 4);
    float* ald   = (float*)alloc((size_t)n * 8 * 4);
    __half* hbuf = (__half*)alloc((size_t)n * 128 * 2);  // GEMM out (h), fp16
    u16* abuf    = (u16*)alloc((size_t)n * 128 * 2);     // GAT out (next GEMM A), bf16
    int* pairs   = (int*)abuf;  // alias: pairs only live during CSR build
    float* out = (float*)d_out;

    const int BS = 256;

    // ---- init (dist + seed bitset + bincnt zero) ----
    k_init<<<nblk(n, BS), BS, 0, stream>>>(seed_mask, dist, rbA, bincnt, n);

    // ---- CSR build: binned counting sort ----
    k_bincount<<<nblk(E4, BS), BS, 0, stream>>>(dst4, bincnt, E4);
    k_binscan<<<1, 512, 0, stream>>>(bincnt, binbase, bincur, rowptr, BINS, (int)E, n);
    k_binscatter<<<nblk(E4, BS), BS, 0, stream>>>(src4, dst4, bincur, pairs, E4, BINS);
    k_binsort<<<BINS, 256, 0, stream>>>(pairs, binbase, rowptr, csr_src, n);

    // ---- BFS hierarchy (double-buffered bitset, fused scan+update) ----
    k_bfs_step<<<nblk(n, BS), BS, 0, stream>>>(rowptr, csr_src, (const u32*)rbA, rbB,
                                               dist, 1, n);
    k_bfs_step<<<nblk(n, BS), BS, 0, stream>>>(rowptr, csr_src, (const u32*)rbB, rbA,
                                               dist, 2, n);
    k_bfs_step<<<nblk(n, BS), BS, 0, stream>>>(rowptr, csr_src, (const u32*)rbA, rbB,
                                               dist, 3, n);

    const int mblocks = (n + 15) / 16;
    const int gmf = (mblocks + 15) / 16;   // 4 waves x MBW=4 m-blocks per block

    // ---- Layer 1: aug(132) -> 8x8, ELU fused (MFMA, x converted to bf16 in LDS) ----
    k_gemm_mfma1<136, 4>
        <<<gmf, 256, 0, stream>>>(x, W1, a1s, a1d, dist, hbuf, als, ald, n);
    k_gat<8, 8, 1, 1, u16><<<nblk(n, 4), 256, 0, stream>>>(
        rowptr, csr_src, hbuf, als, ald, b1, nullptr, nullptr, nullptr, abuf, n);

    // ---- Layer 2: 64 -> 8x16, gate fused (MFMA GEMM, bf16 A) ----
    k_gemm_mfma<64, 128, 9, 8, 16, 72, 4>
        <<<gmf, 256, 0, stream>>>(abuf, W2, a2s, a2d, hbuf, als, ald, n);
    k_gat<8, 16, 2, 2, u16><<<nblk(n, 4), 256, 0, stream>>>(
        rowptr, csr_src, hbuf, als, ald, b2, dist, Wg, bg, abuf, n);

    // ---- Layer 3: 128 -> 1x40, log_softmax fused (MFMA GEMM, bf16 A) ----
    k_gemm_mfma<128, 40, 4, 1, 40, 136, 4>
        <<<gmf, 256, 0, stream>>>(abuf, W3, a3s, a3d, hbuf, als, ald, n);
    k_gat<1, 40, 1, 3, float><<<nblk(n, 4), 256, 0, stream>>>(
        rowptr, csr_src, hbuf, als, ald, b3, nullptr, nullptr, nullptr, out, n);
}

// Round 15
// 361.513 us; speedup vs baseline: 1.2213x; 1.1690x over previous
//
#include <hip/hip_runtime.h>
#include <hip/hip_bf16.h>
#include <hip/hip_fp16.h>
#include <math.h>

#define MAXH 3
#define NSB 8              // 256 nodes per bin
#define NS (1 << NSB)
#define SRCBITS 17         // n < 131072
#define SRCMASK ((1 << SRCBITS) - 1)
#define LOG2E 1.4426950408889634f
typedef unsigned int u32;
typedef unsigned long long u64;
typedef unsigned char u8;
typedef unsigned short u16;

using bf16x8 = __attribute__((ext_vector_type(8))) short;
using f32x4  = __attribute__((ext_vector_type(4))) float;

__device__ __forceinline__ float fexp2(float x) {
#if __has_builtin(__builtin_amdgcn_exp2f)
    return __builtin_amdgcn_exp2f(x);
#else
    return exp2f(x);
#endif
}
__device__ __forceinline__ u16 f2bf(float f) {  // RNE float->bf16
    u32 u = __float_as_uint(f);
    u32 r = ((u >> 16) & 1u) + 0x7fffu;
    return (u16)((u + r) >> 16);
}

// ---------------- fused init: dist + reached bitset (ballot) + bincnt zero ----------
__global__ void k_init(const int* __restrict__ seed_mask, int* dist, u64* rb64,
                       int* bincnt, int n) {
    int i = blockIdx.x * 256 + threadIdx.x;
    int lane = threadIdx.x & 63;
    bool seed = (i < n) && (seed_mask[i] == 0);
    if (i < n) dist[i] = seed ? 0 : (MAXH + 1);
    u64 b = __ballot(seed);
    if (lane == 0 && (i & ~63) < n) rb64[i >> 6] = b;
    if (blockIdx.x == 0) {
        bincnt[threadIdx.x] = 0;
        bincnt[threadIdx.x + 256] = 0;
    }
}

// ---------------- BFS step: scan in-neighbors (old bitset) -> new bitset + dist -----
__global__ void k_bfs_step(const int* __restrict__ rowptr, const int* __restrict__ csr_src,
                           const u32* __restrict__ rbOld, u64* rbNew, int* dist,
                           int h, int n) {
    int i = blockIdx.x * 256 + threadIdx.x;
    int lane = threadIdx.x & 63;
    bool reached = false;
    if (i < n) {
        reached = (rbOld[i >> 5] >> (i & 31)) & 1u;
        if (!reached) {
            int beg = rowptr[i], end = rowptr[i + 1];
            for (int k = beg; k < end; k++) {
                int s = csr_src[k];
                if ((rbOld[s >> 5] >> (s & 31)) & 1u) { reached = true; dist[i] = h; break; }
            }
        }
    }
    u64 b = __ballot(reached);
    if (lane == 0 && (i & ~63) < n) rbNew[i >> 6] = b;
}

// ---------------- CSR build: locality-binned 2-level counting sort (391 bins) -------
__global__ void k_bincount(const int4* __restrict__ dst4, int* bincnt, int E4) {
    __shared__ int cnt[512];
    int t = threadIdx.x;
    cnt[t] = 0; cnt[t + 256] = 0;
    __syncthreads();
    int i = blockIdx.x * 256 + t;
    if (i < E4) {
        int4 d = dst4[i];
        atomicAdd(&cnt[d.x >> NSB], 1);
        atomicAdd(&cnt[d.y >> NSB], 1);
        atomicAdd(&cnt[d.z >> NSB], 1);
        atomicAdd(&cnt[d.w >> NSB], 1);
    }
    __syncthreads();
    if (cnt[t] > 0) atomicAdd(&bincnt[t], cnt[t]);
    if (cnt[t + 256] > 0) atomicAdd(&bincnt[t + 256], cnt[t + 256]);
}

__global__ void k_binscan(const int* __restrict__ bincnt, int* binbase, int* bincur,
                          int* rowptr, int BINS, int E, int n) {
    __shared__ int sd[512];
    int t = threadIdx.x;  // 512 threads
    int v = (t < BINS) ? bincnt[t] : 0;
    sd[t] = v;
    __syncthreads();
    for (int off = 1; off < 512; off <<= 1) {
        int add = (t >= off) ? sd[t - off] : 0;
        __syncthreads();
        sd[t] += add;
        __syncthreads();
    }
    int excl = sd[t] - v;
    if (t < BINS) { binbase[t] = excl; bincur[t] = excl; }
    if (t == 0) { binbase[BINS] = E; rowptr[n] = E; }
}

// 1024-thread blocks: ~10 edges per (block,bin) chunk -> less partial-line write amp
__launch_bounds__(1024)
__global__ void k_binscatter(const int4* __restrict__ src4, const int4* __restrict__ dst4,
                             int* bincur, int* __restrict__ pairs, int E4, int BINS) {
    __shared__ int cnt[512], base[512];
    int t = threadIdx.x;
    if (t < 512) cnt[t] = 0;
    __syncthreads();
    int i = blockIdx.x * 1024 + t;
    int bin[4], rank[4], pack[4];
    bool valid = i < E4;
    if (valid) {
        int4 s = src4[i], d = dst4[i];
        bin[0] = d.x >> NSB; pack[0] = ((d.x & (NS - 1)) << SRCBITS) | s.x;
        bin[1] = d.y >> NSB; pack[1] = ((d.y & (NS - 1)) << SRCBITS) | s.y;
        bin[2] = d.z >> NSB; pack[2] = ((d.z & (NS - 1)) << SRCBITS) | s.z;
        bin[3] = d.w >> NSB; pack[3] = ((d.w & (NS - 1)) << SRCBITS) | s.w;
        rank[0] = atomicAdd(&cnt[bin[0]], 1);
        rank[1] = atomicAdd(&cnt[bin[1]], 1);
        rank[2] = atomicAdd(&cnt[bin[2]], 1);
        rank[3] = atomicAdd(&cnt[bin[3]], 1);
    }
    __syncthreads();
    if (t < 512 && cnt[t] > 0) base[t] = atomicAdd(&bincur[t], cnt[t]);
    __syncthreads();
    if (valid) {
        pairs[base[bin[0]] + rank[0]] = pack[0];
        pairs[base[bin[1]] + rank[1]] = pack[1];
        pairs[base[bin[2]] + rank[2]] = pack[2];
        pairs[base[bin[3]] + rank[3]] = pack[3];
    }
}

__global__ void k_binsort(const int* __restrict__ pairs, const int* __restrict__ binbase,
                          int* __restrict__ rowptr, int* __restrict__ csr_src, int n) {
    __shared__ int hist[NS];  // NS = 256
    const int b = blockIdx.x, t = threadIdx.x;
    const int nbeg = b << NSB;
    const int ebeg = binbase[b];
    const int ecnt = binbase[b + 1] - ebeg;
    hist[t] = 0;
    __syncthreads();
    for (int i = t; i < ecnt; i += 256)
        atomicAdd(&hist[(u32)pairs[ebeg + i] >> SRCBITS], 1);
    for (int d = 1; d < NS; d <<= 1) {
        __syncthreads();
        int idx = (t + 1) * (d << 1) - 1;
        if (idx < NS) hist[idx] += hist[idx - d];
    }
    __syncthreads();
    if (t == 0) hist[NS - 1] = 0;
    for (int d = NS / 2; d >= 1; d >>= 1) {
        __syncthreads();
        int idx = (t + 1) * (d << 1) - 1;
        if (idx < NS) { int tmp = hist[idx - d]; hist[idx - d] = hist[idx]; hist[idx] += tmp; }
    }
    __syncthreads();
    int g0 = nbeg + t;
    if (g0 < n) rowptr[g0] = ebeg + hist[t];
    __syncthreads();
    for (int i = t; i < ecnt; i += 256) {
        int p = pairs[ebeg + i];
        int pos = atomicAdd(&hist[(u32)p >> SRCBITS], 1);
        csr_src[ebeg + pos] = p & SRCMASK;
    }
}

// ---------------- layer-1 MFMA GEMM: fp32 A converted to bf16 in LDS, AUG epilogue ----
template <int SK, int MBW>
__launch_bounds__(256)
__global__ void k_gemm_mfma1(const float* __restrict__ A, const float* __restrict__ W,
                             const float* __restrict__ a_s, const float* __restrict__ a_d,
                             const int* __restrict__ dist, __half* __restrict__ out,
                             float* __restrict__ als, float* __restrict__ ald, int n) {
    constexpr int K = 128, NREAL = 64, NTT = 5, AH = 8, C = 8;
    constexpr int KT = K / 32;
    constexpr int NTCOL = (NTT - 1) * 16;
    __shared__ u16 WT[NTT * 16 * SK];
    __shared__ u16 sAW[4][16 * SK];
    __shared__ float sAug[4][64];
    __shared__ float sAugA[4][16];

    for (int idx = threadIdx.x; idx < NTT * 16 * K; idx += 256) {
        int c = idx / K, k = idx % K;
        float v;
        if (c < NREAL) {
            v = W[k * NREAL + c];
        } else {
            int j = (c - NTCOL) & 7;
            const float* aw = (c < NTCOL + AH) ? a_s : a_d;
            float accv = 0.0f;
            for (int cc = 0; cc < C; cc++) accv += W[k * NREAL + j * C + cc] * aw[j * C + cc];
            v = accv * LOG2E;
        }
        WT[c * SK + k] = f2bf(v);
    }
    {
        int t = threadIdx.x;
        int d = t >> 6, c = t & 63;
        sAug[d][c] = W[(K + d) * NREAL + c];
        if (t < 64) {
            int dd = t >> 4, j = t & 15;
            int hh = j & 7;
            const float* aw = (j < 8) ? a_s : a_d;
            float accv = 0.0f;
            for (int cc = 0; cc < C; cc++)
                accv += W[(K + dd) * NREAL + hh * C + cc] * aw[hh * C + cc];
            sAugA[dd][j] = accv * LOG2E;
        }
    }
    __syncthreads();

    const int lane = threadIdx.x & 63;
    const int l15 = lane & 15;
    const int kg = lane >> 4;
    const int w = threadIdx.x >> 6;
    const int wid = blockIdx.x * 4 + w;

    bf16x8 bfr[NTT][KT];
#pragma unroll
    for (int nt = 0; nt < NTT; nt++)
#pragma unroll
        for (int kt = 0; kt < KT; kt++)
            bfr[nt][kt] = *(const bf16x8*)&WT[(nt * 16 + l15) * SK + kt * 32 + kg * 8];

    for (int mb = 0; mb < MBW; mb++) {
        const int rowbase = (wid * MBW + mb) * 16;
        if (rowbase >= n) break;
        {
            int r = lane >> 2, c4b = lane & 3;
            const float* xr = A + (size_t)(rowbase + r) * K;
#pragma unroll
            for (int j = 0; j < 8; j++) {
                int c4 = c4b + j * 4;
                float4 v = *(const float4*)&xr[c4 * 4];
                ushort4 o;
                o.x = f2bf(v.x); o.y = f2bf(v.y); o.z = f2bf(v.z); o.w = f2bf(v.w);
                *(ushort4*)&sAW[w][r * SK + c4 * 4] = o;
            }
        }
        bf16x8 af[KT];
#pragma unroll
        for (int kt = 0; kt < KT; kt++)
            af[kt] = *(const bf16x8*)&sAW[w][l15 * SK + kt * 32 + kg * 8];
        f32x4 acc[NTT];
#pragma unroll
        for (int nt = 0; nt < NTT; nt++) acc[nt] = f32x4{0.f, 0.f, 0.f, 0.f};
#pragma unroll
        for (int kt = 0; kt < KT; kt++)
#pragma unroll
            for (int nt = 0; nt < NTT; nt++)
                acc[nt] = __builtin_amdgcn_mfma_f32_16x16x32_bf16(af[kt], bfr[nt][kt],
                                                                  acc[nt], 0, 0, 0);
        int rows[4], dd[4];
#pragma unroll
        for (int r = 0; r < 4; r++) {
            rows[r] = rowbase + kg * 4 + r;
            dd[r] = dist[rows[r]];
        }
#pragma unroll
        for (int nt = 0; nt < NTT - 1; nt++) {
            int c = nt * 16 + l15;
#pragma unroll
            for (int r = 0; r < 4; r++) {
                float v = acc[nt][r];
                if (dd[r] <= MAXH) v += sAug[dd[r]][c];
                out[(size_t)rows[r] * NREAL + c] = __float2half(v);
            }
        }
#pragma unroll
        for (int r = 0; r < 4; r++) {
            float v = acc[NTT - 1][r];
            if (dd[r] <= MAXH) v += sAugA[dd[r]][l15];
            if (l15 < AH) als[(size_t)rows[r] * AH + l15] = v;
            else ald[(size_t)rows[r] * AH + (l15 - AH)] = v;
        }
    }
}

// ---------------- MFMA GEMM (A bf16) with fused attn-logit columns ----------------
template <int K, int NREAL, int NTT, int AH, int C, int SK, int MBW>
__launch_bounds__(256)
__global__ void k_gemm_mfma(const u16* __restrict__ A, const float* __restrict__ W,
                            const float* __restrict__ a_s, const float* __restrict__ a_d,
                            __half* __restrict__ out, float* __restrict__ als,
                            float* __restrict__ ald, int n) {
    constexpr int KT = K / 32;
    constexpr int NTCOL = (NTT - 1) * 16;
    __shared__ u16 WT[NTT * 16 * SK];
    for (int idx = threadIdx.x; idx < NTT * 16 * K; idx += 256) {
        int c = idx / K, k = idx % K;
        float v = 0.0f;
        if (c < NREAL) {
            v = W[k * NREAL + c];
        } else if (c >= NTCOL && c < NTCOL + 2 * AH) {
            int j = (c - NTCOL) % AH;
            const float* aw = (c < NTCOL + AH) ? a_s : a_d;
            float accv = 0.0f;
            for (int cc = 0; cc < C; cc++) accv += W[k * NREAL + j * C + cc] * aw[j * C + cc];
            v = accv * LOG2E;
        }
        WT[c * SK + k] = f2bf(v);
    }
    __syncthreads();

    const int lane = threadIdx.x & 63;
    const int l15 = lane & 15;
    const int kg = lane >> 4;
    const int wid = blockIdx.x * 4 + (threadIdx.x >> 6);

    bf16x8 bfr[NTT][KT];
#pragma unroll
    for (int nt = 0; nt < NTT; nt++)
#pragma unroll
        for (int kt = 0; kt < KT; kt++)
            bfr[nt][kt] = *(const bf16x8*)&WT[(nt * 16 + l15) * SK + kt * 32 + kg * 8];

    for (int mb = 0; mb < MBW; mb++) {
        const int rowbase = (wid * MBW + mb) * 16;
        if (rowbase >= n) break;
        bf16x8 af[KT];
#pragma unroll
        for (int kt = 0; kt < KT; kt++)
            af[kt] = *(const bf16x8*)&A[(size_t)(rowbase + l15) * K + kt * 32 + kg * 8];
        f32x4 acc[NTT];
#pragma unroll
        for (int nt = 0; nt < NTT; nt++) acc[nt] = f32x4{0.f, 0.f, 0.f, 0.f};
#pragma unroll
        for (int kt = 0; kt < KT; kt++)
#pragma unroll
            for (int nt = 0; nt < NTT; nt++)
                acc[nt] = __builtin_amdgcn_mfma_f32_16x16x32_bf16(af[kt], bfr[nt][kt],
                                                                  acc[nt], 0, 0, 0);
#pragma unroll
        for (int nt = 0; nt < NTT - 1; nt++) {
            int c = nt * 16 + l15;
            if (c < NREAL) {
#pragma unroll
                for (int r = 0; r < 4; r++) {
                    int row = rowbase + kg * 4 + r;
                    out[(size_t)row * NREAL + c] = __float2half(acc[nt][r]);
                }
            }
        }
#pragma unroll
        for (int r = 0; r < 4; r++) {
            int row = rowbase + kg * 4 + r;
            float v = acc[NTT - 1][r];
            if (l15 < AH) als[(size_t)row * AH + l15] = v;
            else if (l15 < 2 * AH) ald[(size_t)row * AH + (l15 - AH)] = v;
        }
    }
}

// ---------------- fused GAT: EPP edges per wave-pass via edge-group lane split ------
// NL = TOT/CH lanes per edge-group; eg = lane/NL picks which of the EPP edges this
// lane works on. Edge indices broadcast via readlane (SGPR), selected by cndmask —
// no per-edge cross-lane data movement. Merge (shfl) happens once per node.
// MODE: 1=ELU->bf16 (CH=2), 2=gate->bf16 (CH=4), 3=log_softmax->f32 (CH=2)
template <int H, int C, int CH, int EPP, int MODE, typename OT>
__launch_bounds__(256, 8)
__global__ void k_gat(const int* __restrict__ rowptr, const int* __restrict__ csr_src,
                      const __half* __restrict__ h, const float* __restrict__ als,
                      const float* __restrict__ ald, const float* __restrict__ bias,
                      const int* __restrict__ dist, const float* __restrict__ Wg,
                      const float* __restrict__ bg, OT* __restrict__ out, int n) {
    constexpr int TOT = H * C;
    constexpr int NL = TOT / CH;   // lanes per edge-group (32, 32, 20)
    const int lane = threadIdx.x & 63;
    const int node = blockIdx.x * 4 + (threadIdx.x >> 6);
    if (node >= n) return;
    const int beg = rowptr[node];
    const int deg = rowptr[node + 1] - beg;

    const int eg = lane / NL;      // 0..EPP-1 (or EPP.. for idle lanes)
    const int cl = lane % NL;
    const int hd = (cl * CH) / C;
    const float ald_hd = ald[(size_t)node * H + hd];
    const float t0 = als[(size_t)node * H + hd] + ald_hd;
    const float m0 = fmaxf(t0, 0.2f * t0);
    const float c0 = ald_hd - m0;
    const float c1 = 0.2f * ald_hd - m0;

    float s = (eg == 0) ? 1.0f : 0.0f;   // self weight = exp2(0) = 1
    float ax = 0.0f, ay = 0.0f;
    __half2 accLo = __floats2half2_rn(0.f, 0.f), accHi = accLo;
    if (eg == 0) {
        if (MODE == 2) {
            uint2 hv = *(const uint2*)(h + (size_t)node * TOT + cl * CH);
            accLo = *(const __half2*)&hv.x;
            accHi = *(const __half2*)&hv.y;
        } else {
            float2 hf = __half22float2(*(const __half2*)(h + (size_t)node * TOT + cl * CH));
            ax = hf.x; ay = hf.y;
        }
    }

    auto body = [&](int sN, bool valid) {
        float a = als[(size_t)sN * H + hd];
        float v = fmaxf(a + c0, fmaf(a, 0.2f, c1));
        float p = valid ? fexp2(v) : 0.0f;
        s += p;
        if (MODE == 2) {
            __half2 ph = __float2half2_rn(p);
            uint2 hv = *(const uint2*)(h + (size_t)sN * TOT + cl * CH);
            accLo = __hfma2(ph, *(const __half2*)&hv.x, accLo);
            accHi = __hfma2(ph, *(const __half2*)&hv.y, accHi);
        } else {
            float2 hf = __half22float2(*(const __half2*)(h + (size_t)sN * TOT + cl * CH));
            ax += p * hf.x;
            ay += p * hf.y;
        }
    };

    auto group = [&](int sReg, int e0, int cnt) {
        int sN;
        if (EPP == 2) {
            int s0 = __builtin_amdgcn_readlane(sReg, e0);
            int s1 = __builtin_amdgcn_readlane(sReg, e0 + 1);
            sN = eg ? s1 : s0;
        } else {
            int s0 = __builtin_amdgcn_readlane(sReg, e0);
            int s1 = __builtin_amdgcn_readlane(sReg, min(e0 + 1, 63));
            int s2 = __builtin_amdgcn_readlane(sReg, min(e0 + 2, 63));
            sN = (eg == 0) ? s0 : ((eg == 1) ? s1 : s2);
        }
        bool valid = (eg < EPP) && (e0 + eg < cnt);
        body(sN, valid);
    };

    for (int base = 0; base < deg; base += 64) {
        const int myE = base + lane;
        int sReg = (myE < deg) ? csr_src[beg + myE] : 0;
        const int cnt = min(64, deg - base);
        const int ng = (cnt + EPP - 1) / EPP;
        int it = 0;
        for (; it + 2 <= ng; it += 2) {
            group(sReg, it * EPP, cnt);
            group(sReg, (it + 1) * EPP, cnt);
        }
        for (; it < ng; it++) group(sReg, it * EPP, cnt);
    }

    // ---- merge edge-groups (once per node) ----
    if (EPP == 2) {
        s += __shfl_xor(s, 32);
        if (MODE == 2) {
            int lo = __shfl_xor(*(int*)&accLo, 32);
            int hi = __shfl_xor(*(int*)&accHi, 32);
            accLo = __hadd2(accLo, *(const __half2*)&lo);
            accHi = __hadd2(accHi, *(const __half2*)&hi);
        } else {
            ax += __shfl_xor(ax, 32);
            ay += __shfl_xor(ay, 32);
        }
    } else {  // EPP == 3, NL == 20: groups at lanes 0-19, 20-39, 40-59
        float sa = __shfl(s, lane + 20), sb = __shfl(s, lane + 40);
        float xa = __shfl(ax, lane + 20), xb = __shfl(ax, lane + 40);
        float ya = __shfl(ay, lane + 20), yb = __shfl(ay, lane + 40);
        s += sa + sb; ax += xa + xb; ay += ya + yb;
    }

    const bool wlane = (lane < NL);
    const float inv = 1.0f / (s + 1e-16f);

    if (MODE == 1) {  // ELU -> bf16
        if (wlane) {
            float vx = ax * inv + bias[cl * 2];
            float vy = ay * inv + bias[cl * 2 + 1];
            vx = vx > 0.0f ? vx : expm1f(vx);
            vy = vy > 0.0f ? vy : expm1f(vy);
            ushort2 wv; wv.x = f2bf(vx); wv.y = f2bf(vy);
            *(ushort2*)&((u16*)out)[(size_t)node * TOT + cl * 2] = wv;
        }
    } else if (MODE == 2) {  // gate -> bf16 (CH=4; reduction stays in lanes 0-31)
        float2 lo = __half22float2(accLo), hi = __half22float2(accHi);
        float v0 = lo.x * inv + bias[cl * 4];
        float v1 = lo.y * inv + bias[cl * 4 + 1];
        float v2 = hi.x * inv + bias[cl * 4 + 2];
        float v3 = hi.y * inv + bias[cl * 4 + 3];
        float4 wg = *(const float4*)&Wg[cl * 4];
        float part = v0 * wg.x + v1 * wg.y + v2 * wg.z + v3 * wg.w;
#pragma unroll
        for (int off = 16; off > 0; off >>= 1) part += __shfl_xor(part, off);
        int d = dist[node];
        float hop = (d <= MAXH) ? (float)d : 0.0f;
        float g = 1.0f / (1.0f + __expf(-(part + hop * Wg[128] + bg[0])));
        if (wlane) {
            ushort4 wv;
            wv.x = f2bf(v0 * g); wv.y = f2bf(v1 * g);
            wv.z = f2bf(v2 * g); wv.w = f2bf(v3 * g);
            *(ushort4*)&((u16*)out)[(size_t)node * TOT + cl * 4] = wv;
        }
    } else {  // MODE 3: log_softmax -> fp32 (NL=20; reduction within lanes 0-31)
        float vx = ax * inv + bias[cl * 2];
        float vy = ay * inv + bias[cl * 2 + 1];
        float mval = wlane ? fmaxf(vx, vy) : -INFINITY;
#pragma unroll
        for (int off = 16; off > 0; off >>= 1) mval = fmaxf(mval, __shfl_xor(mval, off));
        float ex = wlane ? __expf(vx - mval) + __expf(vy - mval) : 0.0f;
#pragma unroll
        for (int off = 16; off > 0; off >>= 1) ex += __shfl_xor(ex, off);
        float ls = logf(ex);
        if (wlane) {
            *(float2*)&((float*)out)[(size_t)node * TOT + cl * 2] =
                float2{vx - mval - ls, vy - mval - ls};
        }
    }
}

static inline int nblk(long long t, int b) { return (int)((t + b - 1) / b); }

extern "C" void kernel_launch(void* const* d_in, const int* in_sizes, int n_in,
                              void* d_out, int out_size, void* d_ws, size_t ws_size,
                              hipStream_t stream) {
    const float* x = (const float*)d_in[0];
    const int* eidx = (const int*)d_in[1];
    const int* seed_mask = (const int*)d_in[2];
    const float* W1 = (const float*)d_in[3];
    const float* a1s = (const float*)d_in[4];
    const float* a1d = (const float*)d_in[5];
    const float* b1 = (const float*)d_in[6];
    const float* W2 = (const float*)d_in[7];
    const float* a2s = (const float*)d_in[8];
    const float* a2d = (const float*)d_in[9];
    const float* b2 = (const float*)d_in[10];
    const float* W3 = (const float*)d_in[11];
    const float* a3s = (const float*)d_in[12];
    const float* a3d = (const float*)d_in[13];
    const float* b3 = (const float*)d_in[14];
    const float* Wg = (const float*)d_in[15];
    const float* bg = (const float*)d_in[16];

    const int n = in_sizes[0] / 128;        // 100000
    const long long E = in_sizes[1] / 2;    // 1600000
    const int E4 = (int)(E / 4);
    const int4* src4 = (const int4*)eidx;
    const int4* dst4 = (const int4*)(eidx + E);
    const int BINS = (n + NS - 1) >> NSB;   // 391 <= 512
    const int NW64 = (n + 63) / 64;

    char* ws = (char*)d_ws;
    size_t off = 0;
    auto alloc = [&](size_t bytes) -> void* {
        void* p = ws + off;
        off = (off + bytes + 255) & ~(size_t)255;
        return p;
    };
    int* dist    = (int*)alloc((size_t)n * 4);
    u64* rbA     = (u64*)alloc((size_t)NW64 * 8);
    u64* rbB     = (u64*)alloc((size_t)NW64 * 8);
    int* rowptr  = (int*)alloc((size_t)(n + 1) * 4);
    int* bincnt  = (int*)alloc(512 * 4);
    int* binbase = (int*)alloc(513 * 4);
    int* bincur  = (int*)alloc(512 * 4);
    int* csr_src = (int*)alloc((size_t)E * 4);
    float* als   = (float*)alloc((size_t)n * 8 * 4);
    float* ald   = (float*)alloc((size_t)n * 8 * 4);
    __half* hbuf = (__half*)alloc((size_t)n * 128 * 2);  // GEMM out (h), fp16
    u16* abuf    = (u16*)alloc((size_t)n * 128 * 2);     // GAT out (next GEMM A), bf16
    int* pairs   = (int*)abuf;  // alias: pairs only live during CSR build
    float* out = (float*)d_out;

    const int BS = 256;

    // ---- init (dist + seed bitset + bincnt zero) ----
    k_init<<<nblk(n, BS), BS, 0, stream>>>(seed_mask, dist, rbA, bincnt, n);

    // ---- CSR build: binned counting sort ----
    k_bincount<<<nblk(E4, BS), BS, 0, stream>>>(dst4, bincnt, E4);
    k_binscan<<<1, 512, 0, stream>>>(bincnt, binbase, bincur, rowptr, BINS, (int)E, n);
    k_binscatter<<<nblk(E4, 1024), 1024, 0, stream>>>(src4, dst4, bincur, pairs, E4, BINS);
    k_binsort<<<BINS, 256, 0, stream>>>(pairs, binbase, rowptr, csr_src, n);

    // ---- BFS hierarchy (double-buffered bitset, fused scan+update) ----
    k_bfs_step<<<nblk(n, BS), BS, 0, stream>>>(rowptr, csr_src, (const u32*)rbA, rbB,
                                               dist, 1, n);
    k_bfs_step<<<nblk(n, BS), BS, 0, stream>>>(rowptr, csr_src, (const u32*)rbB, rbA,
                                               dist, 2, n);
    k_bfs_step<<<nblk(n, BS), BS, 0, stream>>>(rowptr, csr_src, (const u32*)rbA, rbB,
                                               dist, 3, n);

    const int mblocks = (n + 15) / 16;
    const int gmf = (mblocks + 15) / 16;   // 4 waves x MBW=4 m-blocks per block

    // ---- Layer 1: aug(132) -> 8x8, ELU fused (MFMA, x converted to bf16 in LDS) ----
    k_gemm_mfma1<136, 4>
        <<<gmf, 256, 0, stream>>>(x, W1, a1s, a1d, dist, hbuf, als, ald, n);
    k_gat<8, 8, 2, 2, 1, u16><<<nblk(n, 4), 256, 0, stream>>>(
        rowptr, csr_src, hbuf, als, ald, b1, nullptr, nullptr, nullptr, abuf, n);

    // ---- Layer 2: 64 -> 8x16, gate fused (MFMA GEMM, bf16 A) ----
    k_gemm_mfma<64, 128, 9, 8, 16, 72, 4>
        <<<gmf, 256, 0, stream>>>(abuf, W2, a2s, a2d, hbuf, als, ald, n);
    k_gat<8, 16, 4, 2, 2, u16><<<nblk(n, 4), 256, 0, stream>>>(
        rowptr, csr_src, hbuf, als, ald, b2, dist, Wg, bg, abuf, n);

    // ---- Layer 3: 128 -> 1x40, log_softmax fused (MFMA GEMM, bf16 A) ----
    k_gemm_mfma<128, 40, 4, 1, 40, 136, 4>
        <<<gmf, 256, 0, stream>>>(abuf, W3, a3s, a3d, hbuf, als, ald, n);
    k_gat<1, 40, 2, 3, 3, float><<<nblk(n, 4), 256, 0, stream>>>(
        rowptr, csr_src, hbuf, als, ald, b3, nullptr, nullptr, nullptr, out, n);
}

// Round 16
// 354.212 us; speedup vs baseline: 1.2465x; 1.0206x over previous
//
#include <hip/hip_runtime.h>
#include <hip/hip_bf16.h>
#include <hip/hip_fp16.h>
#include <math.h>

#define MAXH 3
#define NSB 8              // 256 nodes per bin
#define NS (1 << NSB)
#define SRCBITS 17         // n < 131072
#define SRCMASK ((1 << SRCBITS) - 1)
#define LOG2E 1.4426950408889634f
typedef unsigned int u32;
typedef unsigned long long u64;
typedef unsigned char u8;
typedef unsigned short u16;

using bf16x8 = __attribute__((ext_vector_type(8))) short;
using f32x4  = __attribute__((ext_vector_type(4))) float;

__device__ __forceinline__ float fexp2(float x) {
#if __has_builtin(__builtin_amdgcn_exp2f)
    return __builtin_amdgcn_exp2f(x);
#else
    return exp2f(x);
#endif
}
__device__ __forceinline__ u16 f2bf(float f) {  // RNE float->bf16
    u32 u = __float_as_uint(f);
    u32 r = ((u >> 16) & 1u) + 0x7fffu;
    return (u16)((u + r) >> 16);
}

// ---------------- fused init: dist + reached bitset (ballot) + bincnt zero ----------
__global__ void k_init(const int* __restrict__ seed_mask, int* dist, u64* rb64,
                       int* bincnt, int n) {
    int i = blockIdx.x * 256 + threadIdx.x;
    int lane = threadIdx.x & 63;
    bool seed = (i < n) && (seed_mask[i] == 0);
    if (i < n) dist[i] = seed ? 0 : (MAXH + 1);
    u64 b = __ballot(seed);
    if (lane == 0 && (i & ~63) < n) rb64[i >> 6] = b;
    if (blockIdx.x == 0) {
        bincnt[threadIdx.x] = 0;
        bincnt[threadIdx.x + 256] = 0;
    }
}

// ---------------- BFS step: scan in-neighbors (old bitset) -> new bitset + dist -----
__global__ void k_bfs_step(const int* __restrict__ rowptr, const int* __restrict__ csr_src,
                           const u32* __restrict__ rbOld, u64* rbNew, int* dist,
                           int h, int n) {
    int i = blockIdx.x * 256 + threadIdx.x;
    int lane = threadIdx.x & 63;
    bool reached = false;
    if (i < n) {
        reached = (rbOld[i >> 5] >> (i & 31)) & 1u;
        if (!reached) {
            int beg = rowptr[i], end = rowptr[i + 1];
            for (int k = beg; k < end; k++) {
                int s = csr_src[k];
                if ((rbOld[s >> 5] >> (s & 31)) & 1u) { reached = true; dist[i] = h; break; }
            }
        }
    }
    u64 b = __ballot(reached);
    if (lane == 0 && (i & ~63) < n) rbNew[i >> 6] = b;
}

// ---------------- CSR build: locality-binned 2-level counting sort (391 bins) -------
__global__ void k_bincount(const int4* __restrict__ dst4, int* bincnt, int E4) {
    __shared__ int cnt[512];
    int t = threadIdx.x;
    cnt[t] = 0; cnt[t + 256] = 0;
    __syncthreads();
    int i = blockIdx.x * 256 + t;
    if (i < E4) {
        int4 d = dst4[i];
        atomicAdd(&cnt[d.x >> NSB], 1);
        atomicAdd(&cnt[d.y >> NSB], 1);
        atomicAdd(&cnt[d.z >> NSB], 1);
        atomicAdd(&cnt[d.w >> NSB], 1);
    }
    __syncthreads();
    if (cnt[t] > 0) atomicAdd(&bincnt[t], cnt[t]);
    if (cnt[t + 256] > 0) atomicAdd(&bincnt[t + 256], cnt[t + 256]);
}

__global__ void k_binscan(const int* __restrict__ bincnt, int* binbase, int* bincur,
                          int* rowptr, int BINS, int E, int n) {
    __shared__ int sd[512];
    int t = threadIdx.x;  // 512 threads
    int v = (t < BINS) ? bincnt[t] : 0;
    sd[t] = v;
    __syncthreads();
    for (int off = 1; off < 512; off <<= 1) {
        int add = (t >= off) ? sd[t - off] : 0;
        __syncthreads();
        sd[t] += add;
        __syncthreads();
    }
    int excl = sd[t] - v;
    if (t < BINS) { binbase[t] = excl; bincur[t] = excl; }
    if (t == 0) { binbase[BINS] = E; rowptr[n] = E; }
}

// 1024-thread blocks: ~10 edges per (block,bin) chunk -> less partial-line write amp
__launch_bounds__(1024)
__global__ void k_binscatter(const int4* __restrict__ src4, const int4* __restrict__ dst4,
                             int* bincur, int* __restrict__ pairs, int E4, int BINS) {
    __shared__ int cnt[512], base[512];
    int t = threadIdx.x;
    if (t < 512) cnt[t] = 0;
    __syncthreads();
    int i = blockIdx.x * 1024 + t;
    int bin[4], rank[4], pack[4];
    bool valid = i < E4;
    if (valid) {
        int4 s = src4[i], d = dst4[i];
        bin[0] = d.x >> NSB; pack[0] = ((d.x & (NS - 1)) << SRCBITS) | s.x;
        bin[1] = d.y >> NSB; pack[1] = ((d.y & (NS - 1)) << SRCBITS) | s.y;
        bin[2] = d.z >> NSB; pack[2] = ((d.z & (NS - 1)) << SRCBITS) | s.z;
        bin[3] = d.w >> NSB; pack[3] = ((d.w & (NS - 1)) << SRCBITS) | s.w;
        rank[0] = atomicAdd(&cnt[bin[0]], 1);
        rank[1] = atomicAdd(&cnt[bin[1]], 1);
        rank[2] = atomicAdd(&cnt[bin[2]], 1);
        rank[3] = atomicAdd(&cnt[bin[3]], 1);
    }
    __syncthreads();
    if (t < 512 && cnt[t] > 0) base[t] = atomicAdd(&bincur[t], cnt[t]);
    __syncthreads();
    if (valid) {
        pairs[base[bin[0]] + rank[0]] = pack[0];
        pairs[base[bin[1]] + rank[1]] = pack[1];
        pairs[base[bin[2]] + rank[2]] = pack[2];
        pairs[base[bin[3]] + rank[3]] = pack[3];
    }
}

__global__ void k_binsort(const int* __restrict__ pairs, const int* __restrict__ binbase,
                          int* __restrict__ rowptr, int* __restrict__ csr_src, int n) {
    __shared__ int hist[NS];  // NS = 256
    const int b = blockIdx.x, t = threadIdx.x;
    const int nbeg = b << NSB;
    const int ebeg = binbase[b];
    const int ecnt = binbase[b + 1] - ebeg;
    hist[t] = 0;
    __syncthreads();
    for (int i = t; i < ecnt; i += 256)
        atomicAdd(&hist[(u32)pairs[ebeg + i] >> SRCBITS], 1);
    for (int d = 1; d < NS; d <<= 1) {
        __syncthreads();
        int idx = (t + 1) * (d << 1) - 1;
        if (idx < NS) hist[idx] += hist[idx - d];
    }
    __syncthreads();
    if (t == 0) hist[NS - 1] = 0;
    for (int d = NS / 2; d >= 1; d >>= 1) {
        __syncthreads();
        int idx = (t + 1) * (d << 1) - 1;
        if (idx < NS) { int tmp = hist[idx - d]; hist[idx - d] = hist[idx]; hist[idx] += tmp; }
    }
    __syncthreads();
    int g0 = nbeg + t;
    if (g0 < n) rowptr[g0] = ebeg + hist[t];
    __syncthreads();
    for (int i = t; i < ecnt; i += 256) {
        int p = pairs[ebeg + i];
        int pos = atomicAdd(&hist[(u32)p >> SRCBITS], 1);
        csr_src[ebeg + pos] = p & SRCMASK;
    }
}

// ---------------- layer-1 MFMA GEMM: fp32 A converted to bf16 in LDS, AUG epilogue ----
template <int SK, int MBW>
__launch_bounds__(256)
__global__ void k_gemm_mfma1(const float* __restrict__ A, const float* __restrict__ W,
                             const float* __restrict__ a_s, const float* __restrict__ a_d,
                             const int* __restrict__ dist, __half* __restrict__ out,
                             float* __restrict__ als, float* __restrict__ ald, int n) {
    constexpr int K = 128, NREAL = 64, NTT = 5, AH = 8, C = 8;
    constexpr int KT = K / 32;
    constexpr int NTCOL = (NTT - 1) * 16;
    __shared__ u16 WT[NTT * 16 * SK];
    __shared__ u16 sAW[4][16 * SK];
    __shared__ float sAug[4][64];
    __shared__ float sAugA[4][16];

    for (int idx = threadIdx.x; idx < NTT * 16 * K; idx += 256) {
        int c = idx / K, k = idx % K;
        float v;
        if (c < NREAL) {
            v = W[k * NREAL + c];
        } else {
            int j = (c - NTCOL) & 7;
            const float* aw = (c < NTCOL + AH) ? a_s : a_d;
            float accv = 0.0f;
            for (int cc = 0; cc < C; cc++) accv += W[k * NREAL + j * C + cc] * aw[j * C + cc];
            v = accv * LOG2E;
        }
        WT[c * SK + k] = f2bf(v);
    }
    {
        int t = threadIdx.x;
        int d = t >> 6, c = t & 63;
        sAug[d][c] = W[(K + d) * NREAL + c];
        if (t < 64) {
            int dd = t >> 4, j = t & 15;
            int hh = j & 7;
            const float* aw = (j < 8) ? a_s : a_d;
            float accv = 0.0f;
            for (int cc = 0; cc < C; cc++)
                accv += W[(K + dd) * NREAL + hh * C + cc] * aw[hh * C + cc];
            sAugA[dd][j] = accv * LOG2E;
        }
    }
    __syncthreads();

    const int lane = threadIdx.x & 63;
    const int l15 = lane & 15;
    const int kg = lane >> 4;
    const int w = threadIdx.x >> 6;
    const int wid = blockIdx.x * 4 + w;

    bf16x8 bfr[NTT][KT];
#pragma unroll
    for (int nt = 0; nt < NTT; nt++)
#pragma unroll
        for (int kt = 0; kt < KT; kt++)
            bfr[nt][kt] = *(const bf16x8*)&WT[(nt * 16 + l15) * SK + kt * 32 + kg * 8];

    for (int mb = 0; mb < MBW; mb++) {
        const int rowbase = (wid * MBW + mb) * 16;
        if (rowbase >= n) break;
        {
            int r = lane >> 2, c4b = lane & 3;
            const float* xr = A + (size_t)(rowbase + r) * K;
#pragma unroll
            for (int j = 0; j < 8; j++) {
                int c4 = c4b + j * 4;
                float4 v = *(const float4*)&xr[c4 * 4];
                ushort4 o;
                o.x = f2bf(v.x); o.y = f2bf(v.y); o.z = f2bf(v.z); o.w = f2bf(v.w);
                *(ushort4*)&sAW[w][r * SK + c4 * 4] = o;
            }
        }
        bf16x8 af[KT];
#pragma unroll
        for (int kt = 0; kt < KT; kt++)
            af[kt] = *(const bf16x8*)&sAW[w][l15 * SK + kt * 32 + kg * 8];
        f32x4 acc[NTT];
#pragma unroll
        for (int nt = 0; nt < NTT; nt++) acc[nt] = f32x4{0.f, 0.f, 0.f, 0.f};
#pragma unroll
        for (int kt = 0; kt < KT; kt++)
#pragma unroll
            for (int nt = 0; nt < NTT; nt++)
                acc[nt] = __builtin_amdgcn_mfma_f32_16x16x32_bf16(af[kt], bfr[nt][kt],
                                                                  acc[nt], 0, 0, 0);
        int rows[4], dd[4];
#pragma unroll
        for (int r = 0; r < 4; r++) {
            rows[r] = rowbase + kg * 4 + r;
            dd[r] = dist[rows[r]];
        }
#pragma unroll
        for (int nt = 0; nt < NTT - 1; nt++) {
            int c = nt * 16 + l15;
#pragma unroll
            for (int r = 0; r < 4; r++) {
                float v = acc[nt][r];
                if (dd[r] <= MAXH) v += sAug[dd[r]][c];
                out[(size_t)rows[r] * NREAL + c] = __float2half(v);
            }
        }
#pragma unroll
        for (int r = 0; r < 4; r++) {
            float v = acc[NTT - 1][r];
            if (dd[r] <= MAXH) v += sAugA[dd[r]][l15];
            if (l15 < AH) als[(size_t)rows[r] * AH + l15] = v;
            else ald[(size_t)rows[r] * AH + (l15 - AH)] = v;
        }
    }
}

// ---------------- MFMA GEMM (A bf16) with fused attn-logit columns ----------------
template <int K, int NREAL, int NTT, int AH, int C, int SK, int MBW>
__launch_bounds__(256)
__global__ void k_gemm_mfma(const u16* __restrict__ A, const float* __restrict__ W,
                            const float* __restrict__ a_s, const float* __restrict__ a_d,
                            __half* __restrict__ out, float* __restrict__ als,
                            float* __restrict__ ald, int n) {
    constexpr int KT = K / 32;
    constexpr int NTCOL = (NTT - 1) * 16;
    __shared__ u16 WT[NTT * 16 * SK];
    for (int idx = threadIdx.x; idx < NTT * 16 * K; idx += 256) {
        int c = idx / K, k = idx % K;
        float v = 0.0f;
        if (c < NREAL) {
            v = W[k * NREAL + c];
        } else if (c >= NTCOL && c < NTCOL + 2 * AH) {
            int j = (c - NTCOL) % AH;
            const float* aw = (c < NTCOL + AH) ? a_s : a_d;
            float accv = 0.0f;
            for (int cc = 0; cc < C; cc++) accv += W[k * NREAL + j * C + cc] * aw[j * C + cc];
            v = accv * LOG2E;
        }
        WT[c * SK + k] = f2bf(v);
    }
    __syncthreads();

    const int lane = threadIdx.x & 63;
    const int l15 = lane & 15;
    const int kg = lane >> 4;
    const int wid = blockIdx.x * 4 + (threadIdx.x >> 6);

    bf16x8 bfr[NTT][KT];
#pragma unroll
    for (int nt = 0; nt < NTT; nt++)
#pragma unroll
        for (int kt = 0; kt < KT; kt++)
            bfr[nt][kt] = *(const bf16x8*)&WT[(nt * 16 + l15) * SK + kt * 32 + kg * 8];

    for (int mb = 0; mb < MBW; mb++) {
        const int rowbase = (wid * MBW + mb) * 16;
        if (rowbase >= n) break;
        bf16x8 af[KT];
#pragma unroll
        for (int kt = 0; kt < KT; kt++)
            af[kt] = *(const bf16x8*)&A[(size_t)(rowbase + l15) * K + kt * 32 + kg * 8];
        f32x4 acc[NTT];
#pragma unroll
        for (int nt = 0; nt < NTT; nt++) acc[nt] = f32x4{0.f, 0.f, 0.f, 0.f};
#pragma unroll
        for (int kt = 0; kt < KT; kt++)
#pragma unroll
            for (int nt = 0; nt < NTT; nt++)
                acc[nt] = __builtin_amdgcn_mfma_f32_16x16x32_bf16(af[kt], bfr[nt][kt],
                                                                  acc[nt], 0, 0, 0);
#pragma unroll
        for (int nt = 0; nt < NTT - 1; nt++) {
            int c = nt * 16 + l15;
            if (c < NREAL) {
#pragma unroll
                for (int r = 0; r < 4; r++) {
                    int row = rowbase + kg * 4 + r;
                    out[(size_t)row * NREAL + c] = __float2half(acc[nt][r]);
                }
            }
        }
#pragma unroll
        for (int r = 0; r < 4; r++) {
            int row = rowbase + kg * 4 + r;
            float v = acc[NTT - 1][r];
            if (l15 < AH) als[(size_t)row * AH + l15] = v;
            else if (l15 < 2 * AH) ald[(size_t)row * AH + (l15 - AH)] = v;
        }
    }
}

// ---------------- fused GAT: EPP edge-groups + dual chains + 4-wide unroll ---------
// NL = TOT/CH lanes per edge-group; eg = lane/NL picks the edge. Dual accumulator
// chains (X/Y) alternate across the unrolled groups so 8 gathers can be in flight.
// MODE: 1=ELU->bf16 (CH=2), 2=gate->bf16 (CH=4), 3=log_softmax->f32 (CH=2)
template <int H, int C, int CH, int EPP, int MODE, typename OT>
__launch_bounds__(256, 8)
__global__ void k_gat(const int* __restrict__ rowptr, const int* __restrict__ csr_src,
                      const __half* __restrict__ h, const float* __restrict__ als,
                      const float* __restrict__ ald, const float* __restrict__ bias,
                      const int* __restrict__ dist, const float* __restrict__ Wg,
                      const float* __restrict__ bg, OT* __restrict__ out, int n) {
    constexpr int TOT = H * C;
    constexpr int NL = TOT / CH;   // lanes per edge-group (32, 32, 20)
    const int lane = threadIdx.x & 63;
    const int node = blockIdx.x * 4 + (threadIdx.x >> 6);
    if (node >= n) return;
    const int beg = rowptr[node];
    const int deg = rowptr[node + 1] - beg;

    const int eg = lane / NL;      // 0..EPP-1 (or EPP.. for idle lanes)
    const int cl = lane % NL;
    const int hd = (cl * CH) / C;
    const float ald_hd = ald[(size_t)node * H + hd];
    const float t0 = als[(size_t)node * H + hd] + ald_hd;
    const float m0 = fmaxf(t0, 0.2f * t0);
    const float c0 = ald_hd - m0;
    const float c1 = 0.2f * ald_hd - m0;

    // chain X (self-initialized) and chain Y (zero)
    float sX = (eg == 0) ? 1.0f : 0.0f, sY = 0.0f;
    float axX = 0.0f, ayX = 0.0f, axY = 0.0f, ayY = 0.0f;
    __half2 z2 = __floats2half2_rn(0.f, 0.f);
    __half2 loX = z2, hiX = z2, loY = z2, hiY = z2;
    if (eg == 0) {
        if (MODE == 2) {
            uint2 hv = *(const uint2*)(h + (size_t)node * TOT + cl * CH);
            loX = *(const __half2*)&hv.x;
            hiX = *(const __half2*)&hv.y;
        } else {
            float2 hf = __half22float2(*(const __half2*)(h + (size_t)node * TOT + cl * CH));
            axX = hf.x; ayX = hf.y;
        }
    }

    auto body = [&](int sN, bool valid, float& s, float& ax, float& ay,
                    __half2& aLo, __half2& aHi) {
        float a = als[(size_t)sN * H + hd];
        float v = fmaxf(a + c0, fmaf(a, 0.2f, c1));
        float p = valid ? fexp2(v) : 0.0f;
        s += p;
        if (MODE == 2) {
            __half2 ph = __float2half2_rn(p);
            uint2 hv = *(const uint2*)(h + (size_t)sN * TOT + cl * CH);
            aLo = __hfma2(ph, *(const __half2*)&hv.x, aLo);
            aHi = __hfma2(ph, *(const __half2*)&hv.y, aHi);
        } else {
            float2 hf = __half22float2(*(const __half2*)(h + (size_t)sN * TOT + cl * CH));
            ax += p * hf.x;
            ay += p * hf.y;
        }
    };

    auto group = [&](int sReg, int e0, int cnt, float& s, float& ax, float& ay,
                     __half2& aLo, __half2& aHi) {
        int sN;
        if (EPP == 2) {
            int s0 = __builtin_amdgcn_readlane(sReg, e0);
            int s1 = __builtin_amdgcn_readlane(sReg, e0 + 1);
            sN = eg ? s1 : s0;
        } else {
            int s0 = __builtin_amdgcn_readlane(sReg, e0);
            int s1 = __builtin_amdgcn_readlane(sReg, min(e0 + 1, 63));
            int s2 = __builtin_amdgcn_readlane(sReg, min(e0 + 2, 63));
            sN = (eg == 0) ? s0 : ((eg == 1) ? s1 : s2);
        }
        bool valid = (eg < EPP) && (e0 + eg < cnt);
        body(sN, valid, s, ax, ay, aLo, aHi);
    };

    for (int base = 0; base < deg; base += 64) {
        const int myE = base + lane;
        int sReg = (myE < deg) ? csr_src[beg + myE] : 0;
        const int cnt = min(64, deg - base);
        const int ng = (cnt + EPP - 1) / EPP;
        int it = 0;
        for (; it + 4 <= ng; it += 4) {
            group(sReg, (it + 0) * EPP, cnt, sX, axX, ayX, loX, hiX);
            group(sReg, (it + 1) * EPP, cnt, sY, axY, ayY, loY, hiY);
            group(sReg, (it + 2) * EPP, cnt, sX, axX, ayX, loX, hiX);
            group(sReg, (it + 3) * EPP, cnt, sY, axY, ayY, loY, hiY);
        }
        for (; it + 2 <= ng; it += 2) {
            group(sReg, (it + 0) * EPP, cnt, sX, axX, ayX, loX, hiX);
            group(sReg, (it + 1) * EPP, cnt, sY, axY, ayY, loY, hiY);
        }
        for (; it < ng; it++) group(sReg, it * EPP, cnt, sX, axX, ayX, loX, hiX);
    }

    // merge dual chains
    float s = sX + sY;
    float ax = axX + axY, ay = ayX + ayY;
    __half2 accLo = __hadd2(loX, loY), accHi = __hadd2(hiX, hiY);

    // ---- merge edge-groups (once per node) ----
    if (EPP == 2) {
        s += __shfl_xor(s, 32);
        if (MODE == 2) {
            int lo = __shfl_xor(*(int*)&accLo, 32);
            int hi = __shfl_xor(*(int*)&accHi, 32);
            accLo = __hadd2(accLo, *(const __half2*)&lo);
            accHi = __hadd2(accHi, *(const __half2*)&hi);
        } else {
            ax += __shfl_xor(ax, 32);
            ay += __shfl_xor(ay, 32);
        }
    } else {  // EPP == 3, NL == 20: groups at lanes 0-19, 20-39, 40-59
        float sa = __shfl(s, lane + 20), sb = __shfl(s, lane + 40);
        float xa = __shfl(ax, lane + 20), xb = __shfl(ax, lane + 40);
        float ya = __shfl(ay, lane + 20), yb = __shfl(ay, lane + 40);
        s += sa + sb; ax += xa + xb; ay += ya + yb;
    }

    const bool wlane = (lane < NL);
    const float inv = 1.0f / (s + 1e-16f);

    if (MODE == 1) {  // ELU -> bf16
        if (wlane) {
            float vx = ax * inv + bias[cl * 2];
            float vy = ay * inv + bias[cl * 2 + 1];
            vx = vx > 0.0f ? vx : expm1f(vx);
            vy = vy > 0.0f ? vy : expm1f(vy);
            ushort2 wv; wv.x = f2bf(vx); wv.y = f2bf(vy);
            *(ushort2*)&((u16*)out)[(size_t)node * TOT + cl * 2] = wv;
        }
    } else if (MODE == 2) {  // gate -> bf16 (CH=4; reduction stays in lanes 0-31)
        float2 lo = __half22float2(accLo), hi = __half22float2(accHi);
        float v0 = lo.x * inv + bias[cl * 4];
        float v1 = lo.y * inv + bias[cl * 4 + 1];
        float v2 = hi.x * inv + bias[cl * 4 + 2];
        float v3 = hi.y * inv + bias[cl * 4 + 3];
        float4 wg = *(const float4*)&Wg[cl * 4];
        float part = v0 * wg.x + v1 * wg.y + v2 * wg.z + v3 * wg.w;
#pragma unroll
        for (int off = 16; off > 0; off >>= 1) part += __shfl_xor(part, off);
        int d = dist[node];
        float hop = (d <= MAXH) ? (float)d : 0.0f;
        float g = 1.0f / (1.0f + __expf(-(part + hop * Wg[128] + bg[0])));
        if (wlane) {
            ushort4 wv;
            wv.x = f2bf(v0 * g); wv.y = f2bf(v1 * g);
            wv.z = f2bf(v2 * g); wv.w = f2bf(v3 * g);
            *(ushort4*)&((u16*)out)[(size_t)node * TOT + cl * 4] = wv;
        }
    } else {  // MODE 3: log_softmax -> fp32 (NL=20; reduction within lanes 0-31)
        float vx = ax * inv + bias[cl * 2];
        float vy = ay * inv + bias[cl * 2 + 1];
        float mval = wlane ? fmaxf(vx, vy) : -INFINITY;
#pragma unroll
        for (int off = 16; off > 0; off >>= 1) mval = fmaxf(mval, __shfl_xor(mval, off));
        float ex = wlane ? __expf(vx - mval) + __expf(vy - mval) : 0.0f;
#pragma unroll
        for (int off = 16; off > 0; off >>= 1) ex += __shfl_xor(ex, off);
        float ls = logf(ex);
        if (wlane) {
            *(float2*)&((float*)out)[(size_t)node * TOT + cl * 2] =
                float2{vx - mval - ls, vy - mval - ls};
        }
    }
}

static inline int nblk(long long t, int b) { return (int)((t + b - 1) / b); }

extern "C" void kernel_launch(void* const* d_in, const int* in_sizes, int n_in,
                              void* d_out, int out_size, void* d_ws, size_t ws_size,
                              hipStream_t stream) {
    const float* x = (const float*)d_in[0];
    const int* eidx = (const int*)d_in[1];
    const int* seed_mask = (const int*)d_in[2];
    const float* W1 = (const float*)d_in[3];
    const float* a1s = (const float*)d_in[4];
    const float* a1d = (const float*)d_in[5];
    const float* b1 = (const float*)d_in[6];
    const float* W2 = (const float*)d_in[7];
    const float* a2s = (const float*)d_in[8];
    const float* a2d = (const float*)d_in[9];
    const float* b2 = (const float*)d_in[10];
    const float* W3 = (const float*)d_in[11];
    const float* a3s = (const float*)d_in[12];
    const float* a3d = (const float*)d_in[13];
    const float* b3 = (const float*)d_in[14];
    const float* Wg = (const float*)d_in[15];
    const float* bg = (const float*)d_in[16];

    const int n = in_sizes[0] / 128;        // 100000
    const long long E = in_sizes[1] / 2;    // 1600000
    const int E4 = (int)(E / 4);
    const int4* src4 = (const int4*)eidx;
    const int4* dst4 = (const int4*)(eidx + E);
    const int BINS = (n + NS - 1) >> NSB;   // 391 <= 512
    const int NW64 = (n + 63) / 64;

    char* ws = (char*)d_ws;
    size_t off = 0;
    auto alloc = [&](size_t bytes) -> void* {
        void* p = ws + off;
        off = (off + bytes + 255) & ~(size_t)255;
        return p;
    };
    int* dist    = (int*)alloc((size_t)n * 4);
    u64* rbA     = (u64*)alloc((size_t)NW64 * 8);
    u64* rbB     = (u64*)alloc((size_t)NW64 * 8);
    int* rowptr  = (int*)alloc((size_t)(n + 1) * 4);
    int* bincnt  = (int*)alloc(512 * 4);
    int* binbase = (int*)alloc(513 * 4);
    int* bincur  = (int*)alloc(512 * 4);
    int* csr_src = (int*)alloc((size_t)E * 4);
    float* als   = (float*)alloc((size_t)n * 8 * 4);
    float* ald   = (float*)alloc((size_t)n * 8 * 4);
    __half* hbuf = (__half*)alloc((size_t)n * 128 * 2);  // GEMM out (h), fp16
    u16* abuf    = (u16*)alloc((size_t)n * 128 * 2);     // GAT out (next GEMM A), bf16
    int* pairs   = (int*)abuf;  // alias: pairs only live during CSR build
    float* out = (float*)d_out;

    const int BS = 256;

    // ---- init (dist + seed bitset + bincnt zero) ----
    k_init<<<nblk(n, BS), BS, 0, stream>>>(seed_mask, dist, rbA, bincnt, n);

    // ---- CSR build: binned counting sort ----
    k_bincount<<<nblk(E4, BS), BS, 0, stream>>>(dst4, bincnt, E4);
    k_binscan<<<1, 512, 0, stream>>>(bincnt, binbase, bincur, rowptr, BINS, (int)E, n);
    k_binscatter<<<nblk(E4, 1024), 1024, 0, stream>>>(src4, dst4, bincur, pairs, E4, BINS);
    k_binsort<<<BINS, 256, 0, stream>>>(pairs, binbase, rowptr, csr_src, n);

    // ---- BFS hierarchy (double-buffered bitset, fused scan+update) ----
    k_bfs_step<<<nblk(n, BS), BS, 0, stream>>>(rowptr, csr_src, (const u32*)rbA, rbB,
                                               dist, 1, n);
    k_bfs_step<<<nblk(n, BS), BS, 0, stream>>>(rowptr, csr_src, (const u32*)rbB, rbA,
                                               dist, 2, n);
    k_bfs_step<<<nblk(n, BS), BS, 0, stream>>>(rowptr, csr_src, (const u32*)rbA, rbB,
                                               dist, 3, n);

    const int mblocks = (n + 15) / 16;
    const int gmf = (mblocks + 15) / 16;   // 4 waves x MBW=4 m-blocks per block

    // ---- Layer 1: aug(132) -> 8x8, ELU fused (MFMA, x converted to bf16 in LDS) ----
    k_gemm_mfma1<136, 4>
        <<<gmf, 256, 0, stream>>>(x, W1, a1s, a1d, dist, hbuf, als, ald, n);
    k_gat<8, 8, 2, 2, 1, u16><<<nblk(n, 4), 256, 0, stream>>>(
        rowptr, csr_src, hbuf, als, ald, b1, nullptr, nullptr, nullptr, abuf, n);

    // ---- Layer 2: 64 -> 8x16, gate fused (MFMA GEMM, bf16 A) ----
    k_gemm_mfma<64, 128, 9, 8, 16, 72, 4>
        <<<gmf, 256, 0, stream>>>(abuf, W2, a2s, a2d, hbuf, als, ald, n);
    k_gat<8, 16, 4, 2, 2, u16><<<nblk(n, 4), 256, 0, stream>>>(
        rowptr, csr_src, hbuf, als, ald, b2, dist, Wg, bg, abuf, n);

    // ---- Layer 3: 128 -> 1x40, log_softmax fused (MFMA GEMM, bf16 A) ----
    k_gemm_mfma<128, 40, 4, 1, 40, 136, 4>
        <<<gmf, 256, 0, stream>>>(abuf, W3, a3s, a3d, hbuf, als, ald, n);
    k_gat<1, 40, 2, 3, 3, float><<<nblk(n, 4), 256, 0, stream>>>(
        rowptr, csr_src, hbuf, als, ald, b3, nullptr, nullptr, nullptr, out, n);
}